// Round 1
// baseline (1083.001 us; speedup 1.0000x reference)
//
#include <hip/hip_runtime.h>

#define BB 512
#define LDIM 2713
#define ZDIM 58
#define GDIM 8
#define NLAYER 6
#define FFDIM 2048
#define RNAIN 1018
#define CATDIM 528
#define WRSTRIDE 1020

// ---------------- ws layout (floats) ----------------
// cwT    : [LDIM][8]            @ 0        (21704)
// ff2T   : [6][2048][8]         @ 21704    (98304)
// Tmat   : [64][256]            @ 120008   (16384)
// bR     : [64]                 @ 136392   (64)
// Wr     : [64][WRSTRIDE]       @ 136456   (65280)
// bprime : [64]                 @ 201736   (64)
// x      : [512][464]           @ 201800   (237568)   (x0 and xout alias; safe: per-block RAW only)
#define OFF_CWT    0
#define OFF_FF2T   21704
#define OFF_TMAT   120008
#define OFF_BR     136392
#define OFF_WR     136456
#define OFF_BPRIME 201736
#define OFF_X      201800

// ============ prep0: transposes + T = c1r@lin2 + bR = lin2@lin1_b + lin2_b ============
__global__ void prep0_kernel(const float* __restrict__ chem_w, const float* __restrict__ ff2_w,
                             const float* __restrict__ c1_w, const float* __restrict__ lin2_w,
                             const float* __restrict__ lin1_b, const float* __restrict__ lin2_b,
                             float* __restrict__ ws) {
    int tid = blockIdx.x * 256 + threadIdx.x;
    float* cwT  = ws + OFF_CWT;
    float* ff2T = ws + OFF_FF2T;
    float* Tmat = ws + OFF_TMAT;
    float* bR   = ws + OFF_BR;
    if (tid < 21704) {                       // cwT[l][g] = chem_w[g][l]
        int l = tid >> 3, g = tid & 7;
        cwT[tid] = chem_w[g * LDIM + l];
    }
    int t2 = tid - 21704;                    // ff2T[i][f][g] = ff2_w[i][g][f]
    if (t2 >= 0 && t2 < NLAYER * FFDIM * GDIM) {
        int i = t2 / (FFDIM * GDIM);
        int r = t2 % (FFDIM * GDIM);
        int f = r >> 3, g = r & 7;
        ff2T[t2] = ff2_w[i * GDIM * FFDIM + g * FFDIM + f];
    }
    int t3 = tid - 120008;                   // Tmat[j][n] = sum_m c1r[j][m]*lin2[m][n]
    if (t3 >= 0 && t3 < 64 * 256) {
        int j = t3 >> 8, n = t3 & 255;
        float a = 0.f;
        for (int m = 0; m < 64; ++m) a += c1_w[j * CATDIM + m] * lin2_w[m * 256 + n];
        Tmat[t3] = a;
    }
    int t4 = tid - 136392;                   // bR[m] = lin2_b[m] + sum_n lin2[m][n]*lin1_b[n]
    if (t4 >= 0 && t4 < 64) {
        float a = lin2_b[t4];
        for (int n = 0; n < 256; ++n) a += lin2_w[t4 * 256 + n] * lin1_b[n];
        bR[t4] = a;
    }
}

// ============ prep1: Wr = Tmat@lin1 ; bprime = c1_b + c1r@bR ============
__global__ void prep1_kernel(const float* __restrict__ lin1_w, const float* __restrict__ c1_w,
                             const float* __restrict__ c1_b, float* __restrict__ ws) {
    int tid = blockIdx.x * 256 + threadIdx.x;
    const float* Tmat = ws + OFF_TMAT;
    const float* bR   = ws + OFF_BR;
    float* Wr     = ws + OFF_WR;
    float* bprime = ws + OFF_BPRIME;
    if (tid < 64 * WRSTRIDE) {
        int j = tid / WRSTRIDE, k = tid % WRSTRIDE;
        float a = 0.f;
        if (k < RNAIN) {
            for (int n = 0; n < 256; ++n) a += Tmat[j * 256 + n] * lin1_w[n * RNAIN + k];
        }
        Wr[tid] = a;   // pad columns get 0
    } else {
        int j = tid - 64 * WRSTRIDE;
        if (j < 64) {
            float a = c1_b[j];
            for (int m = 0; m < 64; ++m) a += c1_w[j * CATDIM + m] * bR[m];
            bprime[j] = a;
        }
    }
}

// ============ embed: x[b][z][g] = sum_l cwT[l][g]*drug[b][l][z] + pos_w[g][z] ============
__global__ void embed_kernel(const float* __restrict__ drug, const float* __restrict__ pos_w,
                             float* __restrict__ ws) {
    const float* cwT = ws + OFF_CWT;
    float* x0 = ws + OFF_X;
    int b = blockIdx.x;
    int t = threadIdx.x;              // 256 threads, 4 waves
    int w = t >> 6;
    int lane = t & 63;
    int z = (lane < ZDIM) ? lane : (ZDIM - 1);
    bool zok = (lane < ZDIM);
    const float* dp = drug + (size_t)b * (LDIM * ZDIM);
    float acc[8];
    #pragma unroll
    for (int g = 0; g < 8; ++g) acc[g] = 0.f;
    int l0 = w * 679;
    int l1 = (l0 + 679 < LDIM) ? (l0 + 679) : LDIM;
    #pragma unroll 4
    for (int l = l0; l < l1; ++l) {
        float d = dp[l * ZDIM + z];
        const float4* c4 = (const float4*)(cwT + l * 8);
        float4 c0 = c4[0], c1 = c4[1];
        acc[0] += c0.x * d; acc[1] += c0.y * d; acc[2] += c0.z * d; acc[3] += c0.w * d;
        acc[4] += c1.x * d; acc[5] += c1.y * d; acc[6] += c1.z * d; acc[7] += c1.w * d;
    }
    __shared__ float part[4][ZDIM][8];
    if (zok) {
        #pragma unroll
        for (int g = 0; g < 8; ++g) part[w][z][g] = acc[g];
    }
    __syncthreads();
    for (int i = t; i < ZDIM * 8; i += 256) {
        int zz = i >> 3, g = i & 7;
        float s = part[0][zz][g] + part[1][zz][g] + part[2][zz][g] + part[3][zz][g]
                + pos_w[g * ZDIM + zz];
        x0[(size_t)b * 464 + i] = s;
    }
}

// ============ transformer: 6 fused layers, block per batch ============
__global__ __launch_bounds__(512) void transformer_kernel(
    const float* __restrict__ qkv_w, const float* __restrict__ qkv_b,
    const float* __restrict__ out_w, const float* __restrict__ out_b,
    const float* __restrict__ ln1_g, const float* __restrict__ ln1_b,
    const float* __restrict__ ff1_w, const float* __restrict__ ff1_b,
    const float* __restrict__ ff2_b,
    const float* __restrict__ ln2_g, const float* __restrict__ ln2_b,
    float* __restrict__ ws) {
    extern __shared__ float sm[];
    float* W1s   = sm;              // 16384
    float* W2Ts  = sm + 16384;      // 16384
    float* b1s   = sm + 32768;      // 2048
    float* xs    = sm + 34816;      // 512  (64 z padded x 8)
    float* qs    = sm + 35328;      // 480  ([h][60])
    float* ks    = sm + 35808;      // 480
    float* vs    = sm + 36288;      // 480
    float* os    = sm + 36768;      // 480
    float* t2s   = sm + 37248;      // 512
    float* qkvws = sm + 37760;      // 192
    float* qkvbs = sm + 37952;      // 24
    float* outws = sm + 37976;      // 64
    float* outbs = sm + 38040;      // 8
    float* ln1gs = sm + 38048;      // 8
    float* ln1bs = sm + 38056;      // 8
    float* ln2gs = sm + 38064;      // 8
    float* ln2bs = sm + 38072;      // 8
    float* ff2bs = sm + 38080;      // 8   -> total 38088 floats = 152352 B
    float* reds  = sm;              // overlay on W1s after FFN loop (8192 floats)

    const float* ff2T = ws + OFF_FF2T;
    float* xg = ws + OFF_X + (size_t)blockIdx.x * 464;
    int t = threadIdx.x;

    if (t < 464) xs[t] = xg[t];
    else if (t < 512) xs[t] = 0.f;   // zero pad rows z=58..63
    __syncthreads();

    for (int li = 0; li < NLAYER; ++li) {
        // ---- stage layer weights into LDS ----
        {
            const float4* w1g = (const float4*)(ff1_w + li * FFDIM * 8);
            float4* w1d = (float4*)W1s;
            #pragma unroll
            for (int i = 0; i < 8; ++i) w1d[t + i * 512] = w1g[t + i * 512];
            const float4* w2g = (const float4*)(ff2T + li * FFDIM * 8);
            float4* w2d = (float4*)W2Ts;
            #pragma unroll
            for (int i = 0; i < 8; ++i) w2d[t + i * 512] = w2g[t + i * 512];
            ((float4*)b1s)[t] = ((const float4*)(ff1_b + li * FFDIM))[t];
            if (t < 192) qkvws[t] = qkv_w[li * 192 + t];
            if (t < 24)  qkvbs[t] = qkv_b[li * 24 + t];
            if (t < 64)  outws[t] = out_w[li * 64 + t];
            if (t < 8) {
                outbs[t] = out_b[li * 8 + t];
                ln1gs[t] = ln1_g[li * 8 + t]; ln1bs[t] = ln1_b[li * 8 + t];
                ln2gs[t] = ln2_g[li * 8 + t]; ln2bs[t] = ln2_b[li * 8 + t];
                ff2bs[t] = ff2_b[li * 8 + t];
            }
        }
        __syncthreads();

        // ---- qkv projection ----
        if (t < 464) {
            int z = t >> 3, h = t & 7;
            float xv[8];
            #pragma unroll
            for (int g = 0; g < 8; ++g) xv[g] = xs[z * 8 + g];
            #pragma unroll
            for (int p = 0; p < 3; ++p) {
                int j = p * 8 + h;
                float a = qkvbs[j];
                #pragma unroll
                for (int g = 0; g < 8; ++g) a += xv[g] * qkvws[j * 8 + g];
                float* dst = (p == 0) ? qs : (p == 1) ? ks : vs;
                dst[h * 60 + z] = a;
            }
        }
        __syncthreads();

        // ---- attention (HD=1: rank-1 logits per head) ----
        if (t < 464) {
            int h = t & 7, s = t >> 3;
            float q = qs[h * 60 + s];
            const float* kr = ks + h * 60;
            const float* vr = vs + h * 60;
            float m = -1e30f;
            for (int tt = 0; tt < ZDIM; ++tt) m = fmaxf(m, q * kr[tt]);
            float sum = 0.f, oa = 0.f;
            for (int tt = 0; tt < ZDIM; ++tt) {
                float e = __expf(q * kr[tt] - m);
                sum += e;
                oa += e * vr[tt];
            }
            os[h * 60 + s] = oa / sum;
        }
        __syncthreads();

        // ---- out-proj + residual + LN1 ----
        if (t < ZDIM) {
            int z = t;
            float ov[8];
            #pragma unroll
            for (int j = 0; j < 8; ++j) ov[j] = os[j * 60 + z];
            float tmp[8];
            float mu = 0.f;
            #pragma unroll
            for (int g = 0; g < 8; ++g) {
                float a = outbs[g] + xs[z * 8 + g];
                #pragma unroll
                for (int j = 0; j < 8; ++j) a += ov[j] * outws[g * 8 + j];
                tmp[g] = a; mu += a;
            }
            mu *= 0.125f;
            float var = 0.f;
            #pragma unroll
            for (int g = 0; g < 8; ++g) { float d = tmp[g] - mu; var += d * d; }
            var *= 0.125f;
            float inv = rsqrtf(var + 1e-5f);
            #pragma unroll
            for (int g = 0; g < 8; ++g)
                xs[z * 8 + g] = (tmp[g] - mu) * inv * ln1gs[g] + ln1bs[g];
        }
        __syncthreads();

        // ---- FFN: thread = (z-pair zp, f-chunk fc); f = j*16+fc ----
        {
            int zp = t >> 4, fc = t & 15;
            float xa[8], xb[8];
            #pragma unroll
            for (int g = 0; g < 8; ++g) {
                xa[g] = xs[(2 * zp) * 8 + g];
                xb[g] = xs[(2 * zp + 1) * 8 + g];
            }
            float acc[16];
            #pragma unroll
            for (int r = 0; r < 16; ++r) acc[r] = 0.f;
            #pragma unroll 4
            for (int j = 0; j < 128; ++j) {
                int f = j * 16 + fc;
                const float4* wr = (const float4*)(W1s + f * 8);
                float4 w0 = wr[0], w1 = wr[1];
                float bb = b1s[f];
                float h0 = bb + xa[0] * w0.x + xa[1] * w0.y + xa[2] * w0.z + xa[3] * w0.w
                              + xa[4] * w1.x + xa[5] * w1.y + xa[6] * w1.z + xa[7] * w1.w;
                float h1 = bb + xb[0] * w0.x + xb[1] * w0.y + xb[2] * w0.z + xb[3] * w0.w
                              + xb[4] * w1.x + xb[5] * w1.y + xb[6] * w1.z + xb[7] * w1.w;
                h0 = fmaxf(h0, 0.f);
                h1 = fmaxf(h1, 0.f);
                const float4* cr = (const float4*)(W2Ts + f * 8);
                float4 c0 = cr[0], c1 = cr[1];
                acc[0]  += h0 * c0.x; acc[1]  += h0 * c0.y; acc[2]  += h0 * c0.z; acc[3]  += h0 * c0.w;
                acc[4]  += h0 * c1.x; acc[5]  += h0 * c1.y; acc[6]  += h0 * c1.z; acc[7]  += h0 * c1.w;
                acc[8]  += h1 * c0.x; acc[9]  += h1 * c0.y; acc[10] += h1 * c0.z; acc[11] += h1 * c0.w;
                acc[12] += h1 * c1.x; acc[13] += h1 * c1.y; acc[14] += h1 * c1.z; acc[15] += h1 * c1.w;
            }
            __syncthreads();   // everyone done reading W1s/W2Ts -> safe to overlay reds
            float4* rd = (float4*)(reds + t * 16);
            rd[0] = make_float4(acc[0], acc[1], acc[2], acc[3]);
            rd[1] = make_float4(acc[4], acc[5], acc[6], acc[7]);
            rd[2] = make_float4(acc[8], acc[9], acc[10], acc[11]);
            rd[3] = make_float4(acc[12], acc[13], acc[14], acc[15]);
        }
        __syncthreads();
        if (t < 464) {
            int z = t >> 3, g = t & 7;
            int zp = z >> 1, zi = z & 1;
            float ssum = 0.f;
            #pragma unroll
            for (int fc = 0; fc < 16; ++fc)
                ssum += reds[(zp * 16 + fc) * 16 + zi * 8 + g];
            t2s[t] = xs[z * 8 + g] + ssum + ff2bs[g];
        }
        __syncthreads();
        if (t < ZDIM) {
            int z = t;
            float tmp[8];
            float mu = 0.f;
            #pragma unroll
            for (int g = 0; g < 8; ++g) { tmp[g] = t2s[z * 8 + g]; mu += tmp[g]; }
            mu *= 0.125f;
            float var = 0.f;
            #pragma unroll
            for (int g = 0; g < 8; ++g) { float d = tmp[g] - mu; var += d * d; }
            var *= 0.125f;
            float inv = rsqrtf(var + 1e-5f);
            #pragma unroll
            for (int g = 0; g < 8; ++g)
                xs[z * 8 + g] = (tmp[g] - mu) * inv * ln2gs[g] + ln2bs[g];
        }
        __syncthreads();
    }
    if (t < 464) xg[t] = xs[t];
}

// ============ head: out = ((([r2,flat])@c1^T+b)@c2^T+b)@c3^T+b, rna-branch folded ============
__global__ void head_kernel(const float* __restrict__ rna, const float* __restrict__ c1_w,
                            const float* __restrict__ c2_w, const float* __restrict__ c2_b,
                            const float* __restrict__ c3_w, const float* __restrict__ c3_b,
                            const float* __restrict__ ws, float* __restrict__ out) {
    __shared__ float rs[RNAIN];
    __shared__ float fs[464];
    __shared__ float h1s[64];
    __shared__ float h2s[8];
    const float* Wr     = ws + OFF_WR;
    const float* bprime = ws + OFF_BPRIME;
    const float* xfin   = ws + OFF_X;
    int b = blockIdx.x, t = threadIdx.x;   // 64 threads
    const float* rg = rna + (size_t)b * RNAIN;
    for (int i = t; i < RNAIN; i += 64) rs[i] = rg[i];
    const float* xg = xfin + (size_t)b * 464;
    for (int i = t; i < 464; i += 64) fs[i] = xg[i];
    __syncthreads();
    {
        int j = t;
        float a = bprime[j];
        const float4* wr4 = (const float4*)(Wr + j * WRSTRIDE);
        const float4* rs4 = (const float4*)rs;
        for (int k = 0; k < 254; ++k) {
            float4 w = wr4[k], r = rs4[k];
            a += w.x * r.x + w.y * r.y + w.z * r.z + w.w * r.w;
        }
        a += rs[1016] * Wr[j * WRSTRIDE + 1016] + rs[1017] * Wr[j * WRSTRIDE + 1017];
        const float4* cf4 = (const float4*)(c1_w + j * CATDIM + 64);
        const float4* fs4 = (const float4*)fs;
        for (int k = 0; k < 116; ++k) {
            float4 w = cf4[k], r = fs4[k];
            a += w.x * r.x + w.y * r.y + w.z * r.z + w.w * r.w;
        }
        h1s[j] = a;
    }
    __syncthreads();
    if (t < 8) {
        float a = c2_b[t];
        #pragma unroll 8
        for (int m = 0; m < 64; ++m) a += h1s[m] * c2_w[t * 64 + m];
        h2s[t] = a;
    }
    __syncthreads();
    if (t == 0) {
        float a = c3_b[0];
        #pragma unroll
        for (int j = 0; j < 8; ++j) a += h2s[j] * c3_w[j];
        out[b] = a;
    }
}

extern "C" void kernel_launch(void* const* d_in, const int* in_sizes, int n_in,
                              void* d_out, int out_size, void* d_ws, size_t ws_size,
                              hipStream_t stream) {
    const float* rna    = (const float*)d_in[0];
    const float* drug   = (const float*)d_in[1];
    const float* lin1_w = (const float*)d_in[2];
    const float* lin1_b = (const float*)d_in[3];
    const float* lin2_w = (const float*)d_in[4];
    const float* lin2_b = (const float*)d_in[5];
    const float* chem_w = (const float*)d_in[6];
    const float* pos_w  = (const float*)d_in[7];
    const float* qkv_w  = (const float*)d_in[8];
    const float* qkv_b  = (const float*)d_in[9];
    const float* out_w  = (const float*)d_in[10];
    const float* out_b  = (const float*)d_in[11];
    const float* ln1_g  = (const float*)d_in[12];
    const float* ln1_b  = (const float*)d_in[13];
    const float* ff1_w  = (const float*)d_in[14];
    const float* ff1_b  = (const float*)d_in[15];
    const float* ff2_w  = (const float*)d_in[16];
    const float* ff2_b  = (const float*)d_in[17];
    const float* ln2_g  = (const float*)d_in[18];
    const float* ln2_b  = (const float*)d_in[19];
    const float* c1_w   = (const float*)d_in[20];
    const float* c1_b   = (const float*)d_in[21];
    const float* c2_w   = (const float*)d_in[22];
    const float* c2_b   = (const float*)d_in[23];
    const float* c3_w   = (const float*)d_in[24];
    const float* c3_b   = (const float*)d_in[25];
    float* ws  = (float*)d_ws;
    float* out = (float*)d_out;

    hipLaunchKernelGGL(prep0_kernel, dim3(534), dim3(256), 0, stream,
                       chem_w, ff2_w, c1_w, lin2_w, lin1_b, lin2_b, ws);
    hipLaunchKernelGGL(prep1_kernel, dim3(256), dim3(256), 0, stream,
                       lin1_w, c1_w, c1_b, ws);
    hipLaunchKernelGGL(embed_kernel, dim3(BB), dim3(256), 0, stream,
                       drug, pos_w, ws);
    hipLaunchKernelGGL(transformer_kernel, dim3(BB), dim3(512), 38088 * 4, stream,
                       qkv_w, qkv_b, out_w, out_b, ln1_g, ln1_b,
                       ff1_w, ff1_b, ff2_b, ln2_g, ln2_b, ws);
    hipLaunchKernelGGL(head_kernel, dim3(BB), dim3(64), 0, stream,
                       rna, c1_w, c2_w, c2_b, c3_w, c3_b, ws, out);
}

// Round 2
// 920.917 us; speedup vs baseline: 1.1760x; 1.1760x over previous
//
#include <hip/hip_runtime.h>

#define BB 512
#define LDIM 2713
#define ZDIM 58
#define GDIM 8
#define NLAYER 6
#define FFDIM 2048
#define RNAIN 1018
#define CATDIM 528
#define NCAT 1482    // 1018 rna + 464 flat

// ---------------- ws layout (floats) ----------------
#define OFF_CWT    0                    // cwT   [2713][8]        21704
#define OFF_FF2T   21704                // ff2T  [6][2048][8]     98304
#define OFF_TMATT  120008               // TmatT [256][64]        16384
#define OFF_BR     136392               // bR    [64]             64
#define OFF_WCATT  136456               // WcatT [1482][64]       94848
#define OFF_BPRIME 231304               // bprime[64]             64
#define OFF_X      231368               // x     [512][464]       237568  -> total 468936 floats

// ============ prep0: transposes + TmatT = (c1r@lin2)^T + bR ============
__global__ void prep0_kernel(const float* __restrict__ chem_w, const float* __restrict__ ff2_w,
                             const float* __restrict__ c1_w, const float* __restrict__ lin2_w,
                             const float* __restrict__ lin1_b, const float* __restrict__ lin2_b,
                             float* __restrict__ cwT, float* __restrict__ ff2T,
                             float* __restrict__ TmatT, float* __restrict__ bR) {
    int tid = blockIdx.x * 256 + threadIdx.x;
    if (tid < 21704) {                       // cwT[l][g] = chem_w[g][l]
        int l = tid >> 3, g = tid & 7;
        cwT[tid] = chem_w[g * LDIM + l];
    }
    int t2 = tid - 21704;                    // ff2T[i][f][g] = ff2_w[i][g][f]
    if (t2 >= 0 && t2 < NLAYER * FFDIM * GDIM) {
        int i = t2 / (FFDIM * GDIM);
        int r = t2 % (FFDIM * GDIM);
        int f = r >> 3, g = r & 7;
        ff2T[t2] = ff2_w[i * GDIM * FFDIM + g * FFDIM + f];
    }
    int t3 = tid - 120008;                   // TmatT[n][j] = sum_m c1[j][m]*lin2[m][n]
    if (t3 >= 0 && t3 < 256 * 64) {
        int n = t3 >> 6, j = t3 & 63;
        float a = 0.f;
        for (int m = 0; m < 64; ++m) a += c1_w[j * CATDIM + m] * lin2_w[m * 256 + n];
        TmatT[t3] = a;
    }
    int t4 = tid - 136392;                   // bR[m] = lin2_b[m] + sum_n lin2[m][n]*lin1_b[n]
    if (t4 >= 0 && t4 < 64) {
        float a = lin2_b[t4];
        for (int n = 0; n < 256; ++n) a += lin2_w[t4 * 256 + n] * lin1_b[n];
        bR[t4] = a;
    }
}

// ============ prep1: WcatT rows (rna-folded matmul + c1-flat copy) + bprime ============
__global__ void prep1_kernel(const float* __restrict__ lin1_w, const float* __restrict__ c1_w,
                             const float* __restrict__ c1_b, const float* __restrict__ TmatT,
                             const float* __restrict__ bR,
                             float* __restrict__ WcatT, float* __restrict__ bprime) {
    int tid = blockIdx.x * 256 + threadIdx.x;
    if (tid < RNAIN * 64) {                  // WcatT[k][j] = sum_n TmatT[n][j]*lin1_w[n][k]
        int k = tid >> 6, j = tid & 63;
        float a = 0.f;
        #pragma unroll 4
        for (int n = 0; n < 256; ++n) a += TmatT[n * 64 + j] * lin1_w[n * RNAIN + k];
        WcatT[tid] = a;
        return;
    }
    int q = tid - RNAIN * 64;                // flat part: WcatT[1018+kk][j] = c1_w[j][64+kk]
    if (q < 464 * 64) {
        int kk = q >> 6, j = q & 63;
        WcatT[(RNAIN + kk) * 64 + j] = c1_w[j * CATDIM + 64 + kk];
        return;
    }
    int j = q - 464 * 64;                    // bprime[j] = c1_b[j] + sum_m c1[j][m]*bR[m]
    if (j < 64) {
        float a = c1_b[j];
        for (int m = 0; m < 64; ++m) a += c1_w[j * CATDIM + m] * bR[m];
        bprime[j] = a;
    }
}

// ============ embed: x[b][z][g] = sum_l cwT[l][g]*drug[b][l][z] + pos_w[g][z] ============
__global__ __launch_bounds__(512) void embed_kernel(
    const float* __restrict__ drug, const float* __restrict__ pos_w,
    const float* __restrict__ cwT, float* __restrict__ x0) {
    __shared__ float part[8][ZDIM][8];
    int b = blockIdx.x, t = threadIdx.x;
    int w = __builtin_amdgcn_readfirstlane(t >> 6);   // scalar wave id
    int lane = t & 63;
    int z = (lane < ZDIM) ? lane : (ZDIM - 1);
    const float* dp = drug + (size_t)b * (LDIM * ZDIM);
    float acc[8];
    #pragma unroll
    for (int g = 0; g < 8; ++g) acc[g] = 0.f;
    int l0 = w * 340;
    int l1 = (l0 + 340 < LDIM) ? (l0 + 340) : LDIM;
    #pragma unroll 4
    for (int l = l0; l < l1; ++l) {
        float d = dp[l * ZDIM + z];          // per-lane coalesced (232B/row)
        #pragma unroll
        for (int g = 0; g < 8; ++g) acc[g] += cwT[l * 8 + g] * d;   // uniform l -> s_load
    }
    if (lane < ZDIM) {
        #pragma unroll
        for (int g = 0; g < 8; ++g) part[w][z][g] = acc[g];
    }
    __syncthreads();
    if (t < ZDIM * 8) {
        int zz = t >> 3, g = t & 7;
        float s = part[0][zz][g] + part[1][zz][g] + part[2][zz][g] + part[3][zz][g]
                + part[4][zz][g] + part[5][zz][g] + part[6][zz][g] + part[7][zz][g]
                + pos_w[g * ZDIM + zz];
        x0[(size_t)b * 464 + t] = s;
    }
}

// ============ transformer: 6 fused layers, block per batch, scalar-broadcast FFN ============
__global__ __launch_bounds__(512) void transformer_kernel(
    const float* __restrict__ qkv_w, const float* __restrict__ qkv_b,
    const float* __restrict__ out_w, const float* __restrict__ out_b,
    const float* __restrict__ ln1_g, const float* __restrict__ ln1_b,
    const float* __restrict__ ff1_w, const float* __restrict__ ff1_b,
    const float* __restrict__ ff2T, const float* __restrict__ ff2_b,
    const float* __restrict__ ln2_g, const float* __restrict__ ln2_b,
    float* __restrict__ xglob) {
    __shared__ float xs[512];                // 64 z-rows (padded) x 8
    __shared__ float qs[480], ks[480], vs[480], os[480];   // [h][60]
    __shared__ float t2s[464];
    __shared__ float part[8][64][8];         // FFN partials per wave
    __shared__ float qkvws[192], qkvbs[24], outws[64], outbs[8];
    __shared__ float ln1gs[8], ln1bs[8], ln2gs[8], ln2bs[8], ff2bs[8];

    int t = threadIdx.x;
    const int w = __builtin_amdgcn_readfirstlane(t >> 6);   // scalar wave id 0..7
    const int lane = t & 63;
    float* xg = xglob + (size_t)blockIdx.x * 464;

    if (t < 464) xs[t] = xg[t];
    else if (t < 512) xs[t] = 0.f;           // zero pad rows z=58..63
    __syncthreads();

    for (int li = 0; li < NLAYER; ++li) {
        // ---- stage small per-layer weights into LDS ----
        if (t < 192) qkvws[t] = qkv_w[li * 192 + t];
        if (t < 24)  qkvbs[t] = qkv_b[li * 24 + t];
        if (t < 64)  outws[t] = out_w[li * 64 + t];
        if (t < 8) {
            outbs[t] = out_b[li * 8 + t];
            ln1gs[t] = ln1_g[li * 8 + t]; ln1bs[t] = ln1_b[li * 8 + t];
            ln2gs[t] = ln2_g[li * 8 + t]; ln2bs[t] = ln2_b[li * 8 + t];
            ff2bs[t] = ff2_b[li * 8 + t];
        }
        __syncthreads();

        // ---- qkv projection ----
        if (t < 464) {
            int z = t >> 3, h = t & 7;
            float xv[8];
            #pragma unroll
            for (int g = 0; g < 8; ++g) xv[g] = xs[z * 8 + g];
            #pragma unroll
            for (int p = 0; p < 3; ++p) {
                int j = p * 8 + h;
                float a = qkvbs[j];
                #pragma unroll
                for (int g = 0; g < 8; ++g) a += xv[g] * qkvws[j * 8 + g];
                float* dst = (p == 0) ? qs : (p == 1) ? ks : vs;
                dst[h * 60 + z] = a;
            }
        }
        __syncthreads();

        // ---- attention (HD=1: rank-1 logits per head) ----
        if (t < 464) {
            int h = t & 7, s = t >> 3;
            float q = qs[h * 60 + s];
            const float* kr = ks + h * 60;
            const float* vr = vs + h * 60;
            float m = -1e30f;
            for (int tt = 0; tt < ZDIM; ++tt) m = fmaxf(m, q * kr[tt]);
            float sum = 0.f, oa = 0.f;
            for (int tt = 0; tt < ZDIM; ++tt) {
                float e = __expf(q * kr[tt] - m);
                sum += e;
                oa += e * vr[tt];
            }
            os[h * 60 + s] = oa / sum;
        }
        __syncthreads();

        // ---- out-proj + residual + LN1 ----
        if (t < ZDIM) {
            int z = t;
            float ov[8];
            #pragma unroll
            for (int j = 0; j < 8; ++j) ov[j] = os[j * 60 + z];
            float tmp[8];
            float mu = 0.f;
            #pragma unroll
            for (int g = 0; g < 8; ++g) {
                float a = outbs[g] + xs[z * 8 + g];
                #pragma unroll
                for (int j = 0; j < 8; ++j) a += ov[j] * outws[g * 8 + j];
                tmp[g] = a; mu += a;
            }
            mu *= 0.125f;
            float var = 0.f;
            #pragma unroll
            for (int g = 0; g < 8; ++g) { float d = tmp[g] - mu; var += d * d; }
            var *= 0.125f;
            float inv = rsqrtf(var + 1e-5f);
            #pragma unroll
            for (int g = 0; g < 8; ++g)
                xs[z * 8 + g] = (tmp[g] - mu) * inv * ln1gs[g] + ln1bs[g];
        }
        __syncthreads();

        // ---- FFN: lane = z, wave w owns f-slice [w*256, (w+1)*256) ----
        // all weight addresses are wave-uniform -> s_load broadcast, zero LDS traffic
        {
            float xv[8];
            #pragma unroll
            for (int g = 0; g < 8; ++g) xv[g] = xs[lane * 8 + g];
            float acc[8];
            #pragma unroll
            for (int g = 0; g < 8; ++g) acc[g] = 0.f;
            const float* W1p = ff1_w + ((size_t)li * FFDIM + w * 256) * 8;
            const float* W2p = ff2T + ((size_t)li * FFDIM + w * 256) * 8;
            const float* b1p = ff1_b + li * FFDIM + w * 256;
            #pragma unroll 4
            for (int j = 0; j < 256; ++j) {
                float h = b1p[j];
                #pragma unroll
                for (int g = 0; g < 8; ++g) h += xv[g] * W1p[j * 8 + g];
                h = fmaxf(h, 0.f);
                #pragma unroll
                for (int g = 0; g < 8; ++g) acc[g] += h * W2p[j * 8 + g];
            }
            #pragma unroll
            for (int g = 0; g < 8; ++g) part[w][lane][g] = acc[g];
        }
        __syncthreads();

        // ---- reduce partials + residual, then LN2 ----
        if (t < 464) {
            int g = t & 7;
            float s = 0.f;
            #pragma unroll
            for (int ww = 0; ww < 8; ++ww) s += part[ww][t >> 3][g];
            t2s[t] = xs[t] + s + ff2bs[g];
        }
        __syncthreads();
        if (t < ZDIM) {
            int z = t;
            float tmp[8];
            float mu = 0.f;
            #pragma unroll
            for (int g = 0; g < 8; ++g) { tmp[g] = t2s[z * 8 + g]; mu += tmp[g]; }
            mu *= 0.125f;
            float var = 0.f;
            #pragma unroll
            for (int g = 0; g < 8; ++g) { float d = tmp[g] - mu; var += d * d; }
            var *= 0.125f;
            float inv = rsqrtf(var + 1e-5f);
            #pragma unroll
            for (int g = 0; g < 8; ++g)
                xs[z * 8 + g] = (tmp[g] - mu) * inv * ln2gs[g] + ln2bs[g];
        }
        __syncthreads();
    }
    if (t < 464) xg[t] = xs[t];
}

// ============ head: h1 = bprime + WcatT^T @ [rna|flat]; then c2, c3 ============
__global__ __launch_bounds__(512) void head_kernel(
    const float* __restrict__ rna, const float* __restrict__ xfin,
    const float* __restrict__ WcatT, const float* __restrict__ bprime,
    const float* __restrict__ c2_w, const float* __restrict__ c2_b,
    const float* __restrict__ c3_w, const float* __restrict__ c3_b,
    float* __restrict__ out) {
    __shared__ float cat[NCAT];
    __shared__ float partial[8][64];
    __shared__ float h1s[64];
    __shared__ float h2s[8];
    int b = blockIdx.x, t = threadIdx.x;
    const float* rg = rna + (size_t)b * RNAIN;
    for (int i = t; i < RNAIN; i += 512) cat[i] = rg[i];
    const float* fg = xfin + (size_t)b * 464;
    if (t < 464) cat[RNAIN + t] = fg[t];
    __syncthreads();
    int w = __builtin_amdgcn_readfirstlane(t >> 6);
    int j = t & 63;
    int k0 = w * 186;
    int k1 = (k0 + 186 < NCAT) ? (k0 + 186) : NCAT;   // 8*186=1488 >= 1482
    float a = (w == 0) ? bprime[j] : 0.f;
    #pragma unroll 8
    for (int k = k0; k < k1; ++k)
        a += cat[k] * WcatT[k * 64 + j];     // cat[k]: LDS broadcast; WcatT: coalesced
    partial[w][j] = a;
    __syncthreads();
    if (t < 64) {
        float s = 0.f;
        #pragma unroll
        for (int ww = 0; ww < 8; ++ww) s += partial[ww][t];
        h1s[t] = s;
    }
    __syncthreads();
    if (t < 8) {
        float a2 = c2_b[t];
        #pragma unroll 8
        for (int m = 0; m < 64; ++m) a2 += h1s[m] * c2_w[t * 64 + m];
        h2s[t] = a2;
    }
    __syncthreads();
    if (t == 0) {
        float a3 = c3_b[0];
        #pragma unroll
        for (int jj = 0; jj < 8; ++jj) a3 += h2s[jj] * c3_w[jj];
        out[b] = a3;
    }
}

extern "C" void kernel_launch(void* const* d_in, const int* in_sizes, int n_in,
                              void* d_out, int out_size, void* d_ws, size_t ws_size,
                              hipStream_t stream) {
    const float* rna    = (const float*)d_in[0];
    const float* drug   = (const float*)d_in[1];
    const float* lin1_w = (const float*)d_in[2];
    const float* lin1_b = (const float*)d_in[3];
    const float* lin2_w = (const float*)d_in[4];
    const float* lin2_b = (const float*)d_in[5];
    const float* chem_w = (const float*)d_in[6];
    const float* pos_w  = (const float*)d_in[7];
    const float* qkv_w  = (const float*)d_in[8];
    const float* qkv_b  = (const float*)d_in[9];
    const float* out_w  = (const float*)d_in[10];
    const float* out_b  = (const float*)d_in[11];
    const float* ln1_g  = (const float*)d_in[12];
    const float* ln1_b  = (const float*)d_in[13];
    const float* ff1_w  = (const float*)d_in[14];
    const float* ff1_b  = (const float*)d_in[15];
    const float* ff2_w  = (const float*)d_in[16];
    const float* ff2_b  = (const float*)d_in[17];
    const float* ln2_g  = (const float*)d_in[18];
    const float* ln2_b  = (const float*)d_in[19];
    const float* c1_w   = (const float*)d_in[20];
    const float* c1_b   = (const float*)d_in[21];
    const float* c2_w   = (const float*)d_in[22];
    const float* c2_b   = (const float*)d_in[23];
    const float* c3_w   = (const float*)d_in[24];
    const float* c3_b   = (const float*)d_in[25];
    float* ws  = (float*)d_ws;
    float* out = (float*)d_out;

    float* cwT    = ws + OFF_CWT;
    float* ff2T   = ws + OFF_FF2T;
    float* TmatT  = ws + OFF_TMATT;
    float* bR     = ws + OFF_BR;
    float* WcatT  = ws + OFF_WCATT;
    float* bprime = ws + OFF_BPRIME;
    float* x      = ws + OFF_X;

    hipLaunchKernelGGL(prep0_kernel, dim3(534), dim3(256), 0, stream,
                       chem_w, ff2_w, c1_w, lin2_w, lin1_b, lin2_b,
                       cwT, ff2T, TmatT, bR);
    hipLaunchKernelGGL(prep1_kernel, dim3(371), dim3(256), 0, stream,
                       lin1_w, c1_w, c1_b, TmatT, bR, WcatT, bprime);
    hipLaunchKernelGGL(embed_kernel, dim3(BB), dim3(512), 0, stream,
                       drug, pos_w, cwT, x);
    hipLaunchKernelGGL(transformer_kernel, dim3(BB), dim3(512), 0, stream,
                       qkv_w, qkv_b, out_w, out_b, ln1_g, ln1_b,
                       ff1_w, ff1_b, ff2T, ff2_b, ln2_g, ln2_b, x);
    hipLaunchKernelGGL(head_kernel, dim3(BB), dim3(512), 0, stream,
                       rna, x, WcatT, bprime, c2_w, c2_b, c3_w, c3_b, out);
}

// Round 3
// 826.950 us; speedup vs baseline: 1.3096x; 1.1136x over previous
//
#include <hip/hip_runtime.h>

#define BB 512
#define LDIM 2713
#define ZDIM 58
#define GDIM 8
#define NLAYER 6
#define FFDIM 2048
#define RNAIN 1018
#define CATDIM 528
#define NCAT 1482    // 1018 rna-folded + 464 flat

typedef float v2f __attribute__((ext_vector_type(2)));

// ---------------- ws layout (floats) ----------------
#define OFF_CWT    0                    // cwT   [2713][8]          21704
#define OFF_WPACK  21704                // Wpack [6][2048][20]+pad  245824
#define OFF_TMATT  267528               // TmatT [256][64]          16384
#define OFF_BR     283912               // bR    [64]               64
#define OFF_WCATT  283976               // WcatT [1482][64]         94848
#define OFF_BPRIME 378824               // bprime[64]               64
                                        // total 378888 floats (< prior 468936, fits ws)

// ============ prep0: cwT transpose + Wpack + TmatT + bR ============
__global__ void prep0_kernel(const float* __restrict__ chem_w,
                             const float* __restrict__ ff1_w, const float* __restrict__ ff1_b,
                             const float* __restrict__ ff2_w,
                             const float* __restrict__ c1_w, const float* __restrict__ lin2_w,
                             const float* __restrict__ lin1_b, const float* __restrict__ lin2_b,
                             float* __restrict__ cwT, float* __restrict__ Wpack,
                             float* __restrict__ TmatT, float* __restrict__ bR) {
    int tid = blockIdx.x * 256 + threadIdx.x;
    if (tid < 21704) {                       // cwT[l][g] = chem_w[g][l]
        int l = tid >> 3, g = tid & 7;
        cwT[tid] = chem_w[g * LDIM + l];
        return;
    }
    int t2 = tid - 21704;                    // Wpack[(li*2048+f)*20 + c]
    if (t2 < NLAYER * FFDIM) {
        int li = t2 / FFDIM, f = t2 % FFDIM;
        const float4* w1 = (const float4*)(ff1_w + (size_t)li * FFDIM * 8 + f * 8);
        float4 a = w1[0], b = w1[1];
        float w2[8];
        #pragma unroll
        for (int g = 0; g < 8; ++g) w2[g] = ff2_w[(size_t)li * GDIM * FFDIM + g * FFDIM + f];
        float bb = ff1_b[li * FFDIM + f];
        float4* dst = (float4*)(Wpack + (size_t)t2 * 20);
        dst[0] = a;
        dst[1] = b;
        dst[2] = make_float4(w2[0], w2[1], w2[2], w2[3]);
        dst[3] = make_float4(w2[4], w2[5], w2[6], w2[7]);
        dst[4] = make_float4(bb, 0.f, 0.f, 0.f);
        return;
    }
    int t3 = t2 - NLAYER * FFDIM;            // TmatT[n][j] = sum_m c1[j][m]*lin2[m][n]
    if (t3 < 256 * 64) {
        int n = t3 >> 6, j = t3 & 63;
        float a = 0.f;
        for (int m = 0; m < 64; ++m) a += c1_w[j * CATDIM + m] * lin2_w[m * 256 + n];
        TmatT[t3] = a;
        return;
    }
    int t4 = t3 - 256 * 64;                  // bR[m] = lin2_b[m] + sum_n lin2[m][n]*lin1_b[n]
    if (t4 < 64) {
        float a = lin2_b[t4];
        for (int n = 0; n < 256; ++n) a += lin2_w[t4 * 256 + n] * lin1_b[n];
        bR[t4] = a;
    }
}

// ============ prep1: WcatT rows + bprime ============
__global__ void prep1_kernel(const float* __restrict__ lin1_w, const float* __restrict__ c1_w,
                             const float* __restrict__ c1_b, const float* __restrict__ TmatT,
                             const float* __restrict__ bR,
                             float* __restrict__ WcatT, float* __restrict__ bprime) {
    int tid = blockIdx.x * 256 + threadIdx.x;
    if (tid < RNAIN * 64) {                  // WcatT[k][j] = sum_n TmatT[n][j]*lin1_w[n][k]
        int k = tid >> 6, j = tid & 63;
        float a = 0.f;
        #pragma unroll 4
        for (int n = 0; n < 256; ++n) a += TmatT[n * 64 + j] * lin1_w[n * RNAIN + k];
        WcatT[tid] = a;
        return;
    }
    int q = tid - RNAIN * 64;                // WcatT[1018+kk][j] = c1_w[j][64+kk]
    if (q < 464 * 64) {
        int kk = q >> 6, j = q & 63;
        WcatT[(RNAIN + kk) * 64 + j] = c1_w[j * CATDIM + 64 + kk];
        return;
    }
    int j = q - 464 * 64;                    // bprime[j] = c1_b[j] + sum_m c1[j][m]*bR[m]
    if (j < 64) {
        float a = c1_b[j];
        for (int m = 0; m < 64; ++m) a += c1_w[j * CATDIM + m] * bR[m];
        bprime[j] = a;
    }
}

// ============ fused main: embed -> 6 layers -> head, block per batch ============
__global__ __launch_bounds__(512, 4) void main_kernel(
    const float* __restrict__ drug, const float* __restrict__ pos_w,
    const float* __restrict__ cwT, const float* __restrict__ Wpack,
    const float* __restrict__ qkv_w, const float* __restrict__ qkv_b,
    const float* __restrict__ out_w, const float* __restrict__ out_b,
    const float* __restrict__ ln1_g, const float* __restrict__ ln1_b,
    const float* __restrict__ ff2_b,
    const float* __restrict__ ln2_g, const float* __restrict__ ln2_b,
    const float* __restrict__ rna, const float* __restrict__ WcatT,
    const float* __restrict__ bprime,
    const float* __restrict__ c2_w, const float* __restrict__ c2_b,
    const float* __restrict__ c3_w, const float* __restrict__ c3_b,
    float* __restrict__ out) {
    __shared__ float smem[8600];
    float* xs    = smem;            // 512  (64 z-rows padded x 8)
    float* qs    = smem + 512;      // 480  [h][60]
    float* ks    = smem + 992;      // 480
    float* vs    = smem + 1472;     // 480
    float* os    = smem + 1952;     // 512  [s][h]  (== [t])
    float* part  = smem + 2464;     // 4096 [w][64][8]  (reused as cat in head)
    float* qkvws = smem + 6560;     // 1152 [li][24][8]
    float* qkvbs = smem + 7712;     // 144
    float* outws = smem + 7856;     // 384
    float* outbs = smem + 8240;     // 48
    float* l1gs  = smem + 8288;     // 48
    float* l1bs  = smem + 8336;     // 48
    float* l2gs  = smem + 8384;     // 48
    float* l2bs  = smem + 8432;     // 48
    float* f2bs  = smem + 8480;     // 48
    float* h1s   = smem + 8528;     // 64
    float* h2s   = smem + 8592;     // 8

    const int b = blockIdx.x;
    const int t = threadIdx.x;
    const int w = __builtin_amdgcn_readfirstlane(t >> 6);   // wave id 0..7
    const int lane = t & 63;

    // ---- hoist all small per-layer weights (once) ----
    for (int i = t; i < 1152; i += 512) qkvws[i] = qkv_w[i];
    for (int i = t; i < 144; i += 512) qkvbs[i] = qkv_b[i];
    if (t < 384) outws[t] = out_w[t];
    if (t < 48) {
        outbs[t] = out_b[t];
        l1gs[t] = ln1_g[t]; l1bs[t] = ln1_b[t];
        l2gs[t] = ln2_g[t]; l2bs[t] = ln2_b[t];
        f2bs[t] = ff2_b[t];
    }

    // ---- embed: wave w covers l-slice, lane = z ----
    {
        int z = (lane < ZDIM) ? lane : (ZDIM - 1);
        const float* dp = drug + (size_t)b * (LDIM * ZDIM);
        v2f a0 = {0.f, 0.f}, a1 = {0.f, 0.f}, a2 = {0.f, 0.f}, a3 = {0.f, 0.f};
        int l0 = w * 340;
        int l1 = (l0 + 340 < LDIM) ? (l0 + 340) : LDIM;
        int l = l0;
        for (; l + 8 <= l1; l += 8) {
            float d[8];
            #pragma unroll
            for (int i = 0; i < 8; ++i) d[i] = dp[(l + i) * ZDIM + z];
            #pragma unroll
            for (int i = 0; i < 8; ++i) {
                const v2f* cw = (const v2f*)(cwT + (l + i) * 8);
                v2f dd = {d[i], d[i]};
                a0 += cw[0] * dd; a1 += cw[1] * dd; a2 += cw[2] * dd; a3 += cw[3] * dd;
            }
        }
        for (; l < l1; ++l) {
            float d = dp[l * ZDIM + z];
            const v2f* cw = (const v2f*)(cwT + l * 8);
            v2f dd = {d, d};
            a0 += cw[0] * dd; a1 += cw[1] * dd; a2 += cw[2] * dd; a3 += cw[3] * dd;
        }
        v2f* pr = (v2f*)(part + (w * 64 + lane) * 8);
        pr[0] = a0; pr[1] = a1; pr[2] = a2; pr[3] = a3;
    }
    __syncthreads();
    if (t < 464) {
        int z = t >> 3, g = t & 7;
        float s = 0.f;
        #pragma unroll
        for (int ww = 0; ww < 8; ++ww) s += part[(ww * 64 + z) * 8 + g];
        xs[t] = s + pos_w[g * ZDIM + z];
    } else {
        xs[t] = 0.f;   // zero pad rows z=58..63
    }
    __syncthreads();

    // ---- 6 transformer layers ----
    for (int li = 0; li < NLAYER; ++li) {
        // qkv projection: thread = (z, h)
        if (t < 464) {
            int z = t >> 3, h = t & 7;
            const float4* xr = (const float4*)(xs + z * 8);
            float4 x0 = xr[0], x1 = xr[1];
            #pragma unroll
            for (int p = 0; p < 3; ++p) {
                int j = p * 8 + h;
                const float4* wr = (const float4*)(qkvws + li * 192 + j * 8);
                float4 w0 = wr[0], w1 = wr[1];
                float a = qkvbs[li * 24 + j]
                        + x0.x * w0.x + x0.y * w0.y + x0.z * w0.z + x0.w * w0.w
                        + x1.x * w1.x + x1.y * w1.y + x1.z * w1.z + x1.w * w1.w;
                float* dst = (p == 0) ? qs : (p == 1) ? ks : vs;
                dst[h * 60 + z] = a;
            }
        }
        __syncthreads();

        // attention (HD=1, rank-1 logits; LN'd activations -> unshifted softmax safe)
        if (t < 464) {
            int h = t & 7, s = t >> 3;
            float q = qs[h * 60 + s];
            const float4* kr = (const float4*)(ks + h * 60);
            const float4* vr = (const float4*)(vs + h * 60);
            float sum = 0.f, oa = 0.f;
            #pragma unroll 2
            for (int c = 0; c < 14; ++c) {
                float4 k4 = kr[c], v4 = vr[c];
                float e0 = __expf(q * k4.x); sum += e0; oa += e0 * v4.x;
                float e1 = __expf(q * k4.y); sum += e1; oa += e1 * v4.y;
                float e2 = __expf(q * k4.z); sum += e2; oa += e2 * v4.z;
                float e3 = __expf(q * k4.w); sum += e3; oa += e3 * v4.w;
            }
            {
                const float* kk = ks + h * 60;
                const float* vv = vs + h * 60;
                float e0 = __expf(q * kk[56]); sum += e0; oa += e0 * vv[56];
                float e1 = __expf(q * kk[57]); sum += e1; oa += e1 * vv[57];
            }
            os[t] = oa / sum;   // os[s*8+h] == os[t]
        }
        __syncthreads();

        // out-proj + residual + LN1 (per (z,g) thread, shfl row-reduce)
        if (t < 464) {
            int z = t >> 3, g = t & 7;
            const float4* orow = (const float4*)(os + z * 8);
            float4 o0 = orow[0], o1 = orow[1];
            const float4* wr = (const float4*)(outws + li * 64 + g * 8);
            float4 w0 = wr[0], w1 = wr[1];
            float a = outbs[li * 8 + g] + xs[t]
                    + o0.x * w0.x + o0.y * w0.y + o0.z * w0.z + o0.w * w0.w
                    + o1.x * w1.x + o1.y * w1.y + o1.z * w1.z + o1.w * w1.w;
            float s8 = a + __shfl_xor(a, 1);
            s8 += __shfl_xor(s8, 2);
            s8 += __shfl_xor(s8, 4);
            float mu = s8 * 0.125f;
            float d = a - mu;
            float vv = d * d;
            vv += __shfl_xor(vv, 1); vv += __shfl_xor(vv, 2); vv += __shfl_xor(vv, 4);
            float inv = rsqrtf(vv * 0.125f + 1e-5f);
            xs[t] = d * inv * l1gs[li * 8 + g] + l1bs[li * 8 + g];
        }
        __syncthreads();

        // FFN: lane = z, wave owns 256-f slice; packed-fp32 FMAs, 2-deep prefetch
        {
            const float4* xr = (const float4*)(xs + lane * 8);
            float4 x0 = xr[0], x1 = xr[1];
            v2f xv0 = {x0.x, x0.y}, xv1 = {x0.z, x0.w};
            v2f xv2 = {x1.x, x1.y}, xv3 = {x1.z, x1.w};
            v2f a0 = {0.f, 0.f}, a1 = {0.f, 0.f}, a2 = {0.f, 0.f}, a3 = {0.f, 0.f};
            const float4* Wp = (const float4*)(Wpack + (size_t)(li * FFDIM + w * 256) * 20);
            float4 c0 = Wp[0], c1 = Wp[1], c2 = Wp[2], c3 = Wp[3], c4 = Wp[4];
            float4 n0 = Wp[5], n1 = Wp[6], n2 = Wp[7], n3 = Wp[8], n4 = Wp[9];
            #pragma unroll 2
            for (int j = 0; j < 256; ++j) {
                int pb = (j + 2) * 5;
                float4 m0 = Wp[pb], m1 = Wp[pb + 1], m2 = Wp[pb + 2],
                       m3 = Wp[pb + 3], m4 = Wp[pb + 4];
                v2f hv = {c4.x, 0.f};
                hv += (v2f){c0.x, c0.y} * xv0;
                hv += (v2f){c0.z, c0.w} * xv1;
                hv += (v2f){c1.x, c1.y} * xv2;
                hv += (v2f){c1.z, c1.w} * xv3;
                float h = fmaxf(hv.x + hv.y, 0.f);
                v2f hh = {h, h};
                a0 += (v2f){c2.x, c2.y} * hh;
                a1 += (v2f){c2.z, c2.w} * hh;
                a2 += (v2f){c3.x, c3.y} * hh;
                a3 += (v2f){c3.z, c3.w} * hh;
                c0 = n0; c1 = n1; c2 = n2; c3 = n3; c4 = n4;
                n0 = m0; n1 = m1; n2 = m2; n3 = m3; n4 = m4;
            }
            v2f* pr = (v2f*)(part + (w * 64 + lane) * 8);
            pr[0] = a0; pr[1] = a1; pr[2] = a2; pr[3] = a3;
        }
        __syncthreads();

        // reduce partials + residual + LN2
        if (t < 464) {
            int z = t >> 3, g = t & 7;
            float s = 0.f;
            #pragma unroll
            for (int ww = 0; ww < 8; ++ww) s += part[(ww * 64 + z) * 8 + g];
            float a = xs[t] + s + f2bs[li * 8 + g];
            float s8 = a + __shfl_xor(a, 1);
            s8 += __shfl_xor(s8, 2);
            s8 += __shfl_xor(s8, 4);
            float mu = s8 * 0.125f;
            float d = a - mu;
            float vv = d * d;
            vv += __shfl_xor(vv, 1); vv += __shfl_xor(vv, 2); vv += __shfl_xor(vv, 4);
            float inv = rsqrtf(vv * 0.125f + 1e-5f);
            xs[t] = d * inv * l2gs[li * 8 + g] + l2bs[li * 8 + g];
        }
        __syncthreads();
    }

    // ---- head: h1 = bprime + WcatT^T @ [rna-folded | flat] ----
    {
        float* cat = part;   // reuse
        const float* rg = rna + (size_t)b * RNAIN;
        for (int i = t; i < RNAIN; i += 512) cat[i] = rg[i];
        __syncthreads();
        int j = lane;
        int k0 = w * 186;
        int k1 = (k0 + 186 < NCAT) ? (k0 + 186) : NCAT;
        float a = (w == 0) ? bprime[j] : 0.f;
        #pragma unroll 4
        for (int k = k0; k < k1; ++k) {
            float ck = (k < RNAIN) ? cat[k] : xs[k - RNAIN];
            a += ck * WcatT[k * 64 + j];
        }
        qs[w * 64 + j] = a;   // reuse qs as partial buffer
    }
    __syncthreads();
    if (t < 64) {
        float s = 0.f;
        #pragma unroll
        for (int ww = 0; ww < 8; ++ww) s += qs[ww * 64 + t];
        h1s[t] = s;
    }
    __syncthreads();
    if (t < 8) {
        float a2 = c2_b[t];
        #pragma unroll 8
        for (int m = 0; m < 64; ++m) a2 += h1s[m] * c2_w[t * 64 + m];
        h2s[t] = a2;
    }
    __syncthreads();
    if (t == 0) {
        float a3 = c3_b[0];
        #pragma unroll
        for (int jj = 0; jj < 8; ++jj) a3 += h2s[jj] * c3_w[jj];
        out[b] = a3;
    }
}

extern "C" void kernel_launch(void* const* d_in, const int* in_sizes, int n_in,
                              void* d_out, int out_size, void* d_ws, size_t ws_size,
                              hipStream_t stream) {
    const float* rna    = (const float*)d_in[0];
    const float* drug   = (const float*)d_in[1];
    const float* lin1_w = (const float*)d_in[2];
    const float* lin1_b = (const float*)d_in[3];
    const float* lin2_w = (const float*)d_in[4];
    const float* lin2_b = (const float*)d_in[5];
    const float* chem_w = (const float*)d_in[6];
    const float* pos_w  = (const float*)d_in[7];
    const float* qkv_w  = (const float*)d_in[8];
    const float* qkv_b  = (const float*)d_in[9];
    const float* out_w  = (const float*)d_in[10];
    const float* out_b  = (const float*)d_in[11];
    const float* ln1_g  = (const float*)d_in[12];
    const float* ln1_b  = (const float*)d_in[13];
    const float* ff1_w  = (const float*)d_in[14];
    const float* ff1_b  = (const float*)d_in[15];
    const float* ff2_w  = (const float*)d_in[16];
    const float* ff2_b  = (const float*)d_in[17];
    const float* ln2_g  = (const float*)d_in[18];
    const float* ln2_b  = (const float*)d_in[19];
    const float* c1_w   = (const float*)d_in[20];
    const float* c1_b   = (const float*)d_in[21];
    const float* c2_w   = (const float*)d_in[22];
    const float* c2_b   = (const float*)d_in[23];
    const float* c3_w   = (const float*)d_in[24];
    const float* c3_b   = (const float*)d_in[25];
    float* ws  = (float*)d_ws;
    float* out = (float*)d_out;

    float* cwT    = ws + OFF_CWT;
    float* Wpack  = ws + OFF_WPACK;
    float* TmatT  = ws + OFF_TMATT;
    float* bR     = ws + OFF_BR;
    float* WcatT  = ws + OFF_WCATT;
    float* bprime = ws + OFF_BPRIME;

    hipLaunchKernelGGL(prep0_kernel, dim3(198), dim3(256), 0, stream,
                       chem_w, ff1_w, ff1_b, ff2_w, c1_w, lin2_w, lin1_b, lin2_b,
                       cwT, Wpack, TmatT, bR);
    hipLaunchKernelGGL(prep1_kernel, dim3(371), dim3(256), 0, stream,
                       lin1_w, c1_w, c1_b, TmatT, bR, WcatT, bprime);
    hipLaunchKernelGGL(main_kernel, dim3(BB), dim3(512), 0, stream,
                       drug, pos_w, cwT, Wpack, qkv_w, qkv_b, out_w, out_b,
                       ln1_g, ln1_b, ff2_b, ln2_g, ln2_b,
                       rna, WcatT, bprime, c2_w, c2_b, c3_w, c3_b, out);
}

// Round 4
// 778.099 us; speedup vs baseline: 1.3919x; 1.0628x over previous
//
#include <hip/hip_runtime.h>

#define BB 512
#define LDIM 2713
#define ZDIM 58
#define GDIM 8
#define NLAYER 6
#define FFDIM 2048
#define RNAIN 1018
#define CATDIM 528
#define NCAT 1482    // 1018 rna-folded + 464 flat

typedef float v2f __attribute__((ext_vector_type(2)));

// ---------------- ws layout (floats) ----------------
#define OFF_CWT    0                    // cwT   [2713][8]          21704
#define OFF_WPACK  21704                // Wpack [6][2048][20]+pad  245824
#define OFF_TMATT  267528               // TmatT [256][64]          16384
#define OFF_BR     283912               // bR    [64]               64
#define OFF_WCATT  283976               // WcatT [1482][64]         94848
#define OFF_BPRIME 378824               // bprime[64]               64

// ============ prep0: cwT transpose + Wpack + TmatT + bR ============
__global__ void prep0_kernel(const float* __restrict__ chem_w,
                             const float* __restrict__ ff1_w, const float* __restrict__ ff1_b,
                             const float* __restrict__ ff2_w,
                             const float* __restrict__ c1_w, const float* __restrict__ lin2_w,
                             const float* __restrict__ lin1_b, const float* __restrict__ lin2_b,
                             float* __restrict__ cwT, float* __restrict__ Wpack,
                             float* __restrict__ TmatT, float* __restrict__ bR) {
    int tid = blockIdx.x * 256 + threadIdx.x;
    if (tid < 21704) {                       // cwT[l][g] = chem_w[g][l]
        int l = tid >> 3, g = tid & 7;
        cwT[tid] = chem_w[g * LDIM + l];
        return;
    }
    int t2 = tid - 21704;                    // Wpack[(li*2048+f)*20 + c]: W1 row|W2 row|b1
    if (t2 < NLAYER * FFDIM) {
        int li = t2 / FFDIM, f = t2 % FFDIM;
        const float4* w1 = (const float4*)(ff1_w + (size_t)li * FFDIM * 8 + f * 8);
        float4 a = w1[0], b = w1[1];
        float w2[8];
        #pragma unroll
        for (int g = 0; g < 8; ++g) w2[g] = ff2_w[(size_t)li * GDIM * FFDIM + g * FFDIM + f];
        float bb = ff1_b[li * FFDIM + f];
        float4* dst = (float4*)(Wpack + (size_t)t2 * 20);
        dst[0] = a;
        dst[1] = b;
        dst[2] = make_float4(w2[0], w2[1], w2[2], w2[3]);
        dst[3] = make_float4(w2[4], w2[5], w2[6], w2[7]);
        dst[4] = make_float4(bb, 0.f, 0.f, 0.f);
        return;
    }
    int t3 = t2 - NLAYER * FFDIM;            // TmatT[n][j] = sum_m c1[j][m]*lin2[m][n]
    if (t3 < 256 * 64) {
        int n = t3 >> 6, j = t3 & 63;
        float a = 0.f;
        for (int m = 0; m < 64; ++m) a += c1_w[j * CATDIM + m] * lin2_w[m * 256 + n];
        TmatT[t3] = a;
        return;
    }
    int t4 = t3 - 256 * 64;                  // bR[m] = lin2_b[m] + sum_n lin2[m][n]*lin1_b[n]
    if (t4 < 64) {
        float a = lin2_b[t4];
        for (int n = 0; n < 256; ++n) a += lin2_w[t4 * 256 + n] * lin1_b[n];
        bR[t4] = a;
    }
}

// ============ prep1: WcatT rows + bprime ============
__global__ void prep1_kernel(const float* __restrict__ lin1_w, const float* __restrict__ c1_w,
                             const float* __restrict__ c1_b, const float* __restrict__ TmatT,
                             const float* __restrict__ bR,
                             float* __restrict__ WcatT, float* __restrict__ bprime) {
    int tid = blockIdx.x * 256 + threadIdx.x;
    if (tid < RNAIN * 64) {                  // WcatT[k][j] = sum_n TmatT[n][j]*lin1_w[n][k]
        int k = tid >> 6, j = tid & 63;
        float a = 0.f;
        #pragma unroll 4
        for (int n = 0; n < 256; ++n) a += TmatT[n * 64 + j] * lin1_w[n * RNAIN + k];
        WcatT[tid] = a;
        return;
    }
    int q = tid - RNAIN * 64;                // WcatT[1018+kk][j] = c1_w[j][64+kk]
    if (q < 464 * 64) {
        int kk = q >> 6, j = q & 63;
        WcatT[(RNAIN + kk) * 64 + j] = c1_w[j * CATDIM + 64 + kk];
        return;
    }
    int j = q - 464 * 64;                    // bprime[j] = c1_b[j] + sum_m c1[j][m]*bR[m]
    if (j < 64) {
        float a = c1_b[j];
        for (int m = 0; m < 64; ++m) a += c1_w[j * CATDIM + m] * bR[m];
        bprime[j] = a;
    }
}

// ============ fused main: embed -> 6 layers -> head, block per batch, 1024 thr ============
__global__ __launch_bounds__(1024, 8) void main_kernel(
    const float* __restrict__ drug, const float* __restrict__ pos_w,
    const float* __restrict__ cwT, const float* __restrict__ Wpack,
    const float* __restrict__ qkv_w, const float* __restrict__ qkv_b,
    const float* __restrict__ out_w, const float* __restrict__ out_b,
    const float* __restrict__ ln1_g, const float* __restrict__ ln1_b,
    const float* __restrict__ ff2_b,
    const float* __restrict__ ln2_g, const float* __restrict__ ln2_b,
    const float* __restrict__ rna, const float* __restrict__ WcatT,
    const float* __restrict__ bprime,
    const float* __restrict__ c2_w, const float* __restrict__ c2_b,
    const float* __restrict__ c3_w, const float* __restrict__ c3_b,
    float* __restrict__ out) {
    __shared__ float smem[12712];
    float* xs    = smem;            // 512  (64 z-rows padded x 8)
    float* qs    = smem + 512;      // 480  [h][60]
    float* ks    = smem + 992;      // 480
    float* vs    = smem + 1472;     // 480
    float* os    = smem + 1952;     // 512  [s][h]  (== [t])
    float* part  = smem + 2464;     // 8192 [w16][64][8]  (reused as cat+partials in head)
    float* qkvws = smem + 10656;    // 1152 [li][24][8]
    float* qkvbs = smem + 11808;    // 144
    float* outws = smem + 11952;    // 384
    float* outbs = smem + 12336;    // 48
    float* l1gs  = smem + 12384;    // 48
    float* l1bs  = smem + 12432;    // 48
    float* l2gs  = smem + 12480;    // 48
    float* l2bs  = smem + 12528;    // 48
    float* f2bs  = smem + 12576;    // 48
    float* h1s   = smem + 12624;    // 64
    float* h2s   = smem + 12688;    // 8  -> 12696 total

    const int b = blockIdx.x;
    const int t = threadIdx.x;
    const int w = __builtin_amdgcn_readfirstlane(t >> 6);   // wave id 0..15
    const int lane = t & 63;

    // ---- hoist all small per-layer weights (once) ----
    for (int i = t; i < 1152; i += 1024) qkvws[i] = qkv_w[i];
    if (t < 144) qkvbs[t] = qkv_b[t];
    if (t < 384) outws[t] = out_w[t];
    if (t < 48) {
        outbs[t] = out_b[t];
        l1gs[t] = ln1_g[t]; l1bs[t] = ln1_b[t];
        l2gs[t] = ln2_g[t]; l2bs[t] = ln2_b[t];
        f2bs[t] = ff2_b[t];
    }

    // ---- embed: wave w covers l-slice (170), lane = z ----
    {
        int z = (lane < ZDIM) ? lane : (ZDIM - 1);
        const float* dp = drug + (size_t)b * (LDIM * ZDIM);
        v2f a0 = {0.f, 0.f}, a1 = {0.f, 0.f}, a2 = {0.f, 0.f}, a3 = {0.f, 0.f};
        int l0 = w * 170;
        int l1 = (l0 + 170 < LDIM) ? (l0 + 170) : LDIM;
        int l = l0;
        for (; l + 8 <= l1; l += 8) {
            float d[8];
            #pragma unroll
            for (int i = 0; i < 8; ++i) d[i] = dp[(l + i) * ZDIM + z];
            #pragma unroll
            for (int i = 0; i < 8; ++i) {
                const v2f* cw = (const v2f*)(cwT + (l + i) * 8);
                v2f dd = {d[i], d[i]};
                a0 += cw[0] * dd; a1 += cw[1] * dd; a2 += cw[2] * dd; a3 += cw[3] * dd;
            }
        }
        for (; l < l1; ++l) {
            float d = dp[l * ZDIM + z];
            const v2f* cw = (const v2f*)(cwT + l * 8);
            v2f dd = {d, d};
            a0 += cw[0] * dd; a1 += cw[1] * dd; a2 += cw[2] * dd; a3 += cw[3] * dd;
        }
        v2f* pr = (v2f*)(part + (w * 64 + lane) * 8);
        pr[0] = a0; pr[1] = a1; pr[2] = a2; pr[3] = a3;
    }
    __syncthreads();
    if (t < 512) {
        if (t < 464) {
            int z = t >> 3, g = t & 7;
            float s = 0.f;
            #pragma unroll
            for (int ww = 0; ww < 16; ++ww) s += part[(ww * 64 + z) * 8 + g];
            xs[t] = s + pos_w[g * ZDIM + z];
        } else {
            xs[t] = 0.f;   // zero pad rows z=58..63
        }
    }
    __syncthreads();

    // ---- 6 transformer layers ----
    for (int li = 0; li < NLAYER; ++li) {
        // qkv projection: thread = (z, h)
        if (t < 464) {
            int z = t >> 3, h = t & 7;
            const float4* xr = (const float4*)(xs + z * 8);
            float4 x0 = xr[0], x1 = xr[1];
            #pragma unroll
            for (int p = 0; p < 3; ++p) {
                int j = p * 8 + h;
                const float4* wr = (const float4*)(qkvws + li * 192 + j * 8);
                float4 w0 = wr[0], w1 = wr[1];
                float a = qkvbs[li * 24 + j]
                        + x0.x * w0.x + x0.y * w0.y + x0.z * w0.z + x0.w * w0.w
                        + x1.x * w1.x + x1.y * w1.y + x1.z * w1.z + x1.w * w1.w;
                float* dst = (p == 0) ? qs : (p == 1) ? ks : vs;
                dst[h * 60 + z] = a;
            }
        }
        __syncthreads();

        // attention (HD=1, rank-1 logits; LN'd activations -> unshifted softmax safe)
        if (t < 464) {
            int h = t & 7, s = t >> 3;
            float q = qs[h * 60 + s];
            const float4* kr = (const float4*)(ks + h * 60);
            const float4* vr = (const float4*)(vs + h * 60);
            float sum = 0.f, oa = 0.f;
            #pragma unroll 2
            for (int c = 0; c < 14; ++c) {
                float4 k4 = kr[c], v4 = vr[c];
                float e0 = __expf(q * k4.x); sum += e0; oa += e0 * v4.x;
                float e1 = __expf(q * k4.y); sum += e1; oa += e1 * v4.y;
                float e2 = __expf(q * k4.z); sum += e2; oa += e2 * v4.z;
                float e3 = __expf(q * k4.w); sum += e3; oa += e3 * v4.w;
            }
            {
                const float* kk = ks + h * 60;
                const float* vv = vs + h * 60;
                float e0 = __expf(q * kk[56]); sum += e0; oa += e0 * vv[56];
                float e1 = __expf(q * kk[57]); sum += e1; oa += e1 * vv[57];
            }
            os[t] = oa / sum;   // os[s*8+h] == os[t]
        }
        __syncthreads();

        // out-proj + residual + LN1 (per (z,g) thread, shfl row-reduce)
        if (t < 464) {
            int z = t >> 3, g = t & 7;
            const float4* orow = (const float4*)(os + z * 8);
            float4 o0 = orow[0], o1 = orow[1];
            const float4* wr = (const float4*)(outws + li * 64 + g * 8);
            float4 w0 = wr[0], w1 = wr[1];
            float a = outbs[li * 8 + g] + xs[t]
                    + o0.x * w0.x + o0.y * w0.y + o0.z * w0.z + o0.w * w0.w
                    + o1.x * w1.x + o1.y * w1.y + o1.z * w1.z + o1.w * w1.w;
            float s8 = a + __shfl_xor(a, 1);
            s8 += __shfl_xor(s8, 2);
            s8 += __shfl_xor(s8, 4);
            float mu = s8 * 0.125f;
            float d = a - mu;
            float vv = d * d;
            vv += __shfl_xor(vv, 1); vv += __shfl_xor(vv, 2); vv += __shfl_xor(vv, 4);
            float inv = rsqrtf(vv * 0.125f + 1e-5f);
            xs[t] = d * inv * l1gs[li * 8 + g] + l1bs[li * 8 + g];
        }
        __syncthreads();

        // ---- FFN: lane = z, wave owns 128-f slice; SGPR weights, 2x unroll pipeline ----
        {
            const float4* xr = (const float4*)(xs + lane * 8);
            float4 x0 = xr[0], x1 = xr[1];
            float xv[8] = {x0.x, x0.y, x0.z, x0.w, x1.x, x1.y, x1.z, x1.w};
            float acc[8];
            #pragma unroll
            for (int g = 0; g < 8; ++g) acc[g] = 0.f;
            const float* Wp = Wpack + (size_t)(li * FFDIM + w * 128) * 20;
            float cur[20], nxt[20];
            #pragma unroll
            for (int c = 0; c < 20; ++c) cur[c] = Wp[c];
            for (int j = 0; j < 128; j += 2) {
                const float* p1 = Wp + (j + 1) * 20;
                #pragma unroll
                for (int c = 0; c < 20; ++c) nxt[c] = p1[c];
                {
                    float h = cur[16];
                    #pragma unroll
                    for (int g = 0; g < 8; ++g) h += xv[g] * cur[g];
                    h = fmaxf(h, 0.f);
                    #pragma unroll
                    for (int g = 0; g < 8; ++g) acc[g] += h * cur[8 + g];
                }
                const float* p2 = Wp + (j + 2) * 20;   // j=126 reads pad past slice: valid ws mem
                #pragma unroll
                for (int c = 0; c < 20; ++c) cur[c] = p2[c];
                {
                    float h = nxt[16];
                    #pragma unroll
                    for (int g = 0; g < 8; ++g) h += xv[g] * nxt[g];
                    h = fmaxf(h, 0.f);
                    #pragma unroll
                    for (int g = 0; g < 8; ++g) acc[g] += h * nxt[8 + g];
                }
            }
            v2f* pr = (v2f*)(part + (w * 64 + lane) * 8);
            pr[0] = (v2f){acc[0], acc[1]};
            pr[1] = (v2f){acc[2], acc[3]};
            pr[2] = (v2f){acc[4], acc[5]};
            pr[3] = (v2f){acc[6], acc[7]};
        }
        __syncthreads();

        // reduce partials + residual + LN2
        if (t < 464) {
            int z = t >> 3, g = t & 7;
            float s = 0.f;
            #pragma unroll
            for (int ww = 0; ww < 16; ++ww) s += part[(ww * 64 + z) * 8 + g];
            float a = xs[t] + s + f2bs[li * 8 + g];
            float s8 = a + __shfl_xor(a, 1);
            s8 += __shfl_xor(s8, 2);
            s8 += __shfl_xor(s8, 4);
            float mu = s8 * 0.125f;
            float d = a - mu;
            float vv = d * d;
            vv += __shfl_xor(vv, 1); vv += __shfl_xor(vv, 2); vv += __shfl_xor(vv, 4);
            float inv = rsqrtf(vv * 0.125f + 1e-5f);
            xs[t] = d * inv * l2gs[li * 8 + g] + l2bs[li * 8 + g];
        }
        __syncthreads();
    }

    // ---- head: h1 = bprime + WcatT^T @ [rna-folded | flat] ----
    {
        float* cat = part;               // [0..1017]
        float* partial = part + 4096;    // [16][64]
        const float* rg = rna + (size_t)b * RNAIN;
        for (int i = t; i < RNAIN; i += 1024) cat[i] = rg[i];
        __syncthreads();
        int j = lane;
        int k0 = w * 93;
        int k1 = (k0 + 93 < NCAT) ? (k0 + 93) : NCAT;   // 16*93=1488 >= 1482
        float a = (w == 0) ? bprime[j] : 0.f;
        #pragma unroll 4
        for (int k = k0; k < k1; ++k) {
            float ck = (k < RNAIN) ? cat[k] : xs[k - RNAIN];
            a += ck * WcatT[k * 64 + j];
        }
        partial[w * 64 + j] = a;
        __syncthreads();
        if (t < 64) {
            float s = 0.f;
            #pragma unroll
            for (int ww = 0; ww < 16; ++ww) s += partial[ww * 64 + t];
            h1s[t] = s;
        }
    }
    __syncthreads();
    if (t < 8) {
        float a2 = c2_b[t];
        #pragma unroll 8
        for (int m = 0; m < 64; ++m) a2 += h1s[m] * c2_w[t * 64 + m];
        h2s[t] = a2;
    }
    __syncthreads();
    if (t == 0) {
        float a3 = c3_b[0];
        #pragma unroll
        for (int jj = 0; jj < 8; ++jj) a3 += h2s[jj] * c3_w[jj];
        out[b] = a3;
    }
}

extern "C" void kernel_launch(void* const* d_in, const int* in_sizes, int n_in,
                              void* d_out, int out_size, void* d_ws, size_t ws_size,
                              hipStream_t stream) {
    const float* rna    = (const float*)d_in[0];
    const float* drug   = (const float*)d_in[1];
    const float* lin1_w = (const float*)d_in[2];
    const float* lin1_b = (const float*)d_in[3];
    const float* lin2_w = (const float*)d_in[4];
    const float* lin2_b = (const float*)d_in[5];
    const float* chem_w = (const float*)d_in[6];
    const float* pos_w  = (const float*)d_in[7];
    const float* qkv_w  = (const float*)d_in[8];
    const float* qkv_b  = (const float*)d_in[9];
    const float* out_w  = (const float*)d_in[10];
    const float* out_b  = (const float*)d_in[11];
    const float* ln1_g  = (const float*)d_in[12];
    const float* ln1_b  = (const float*)d_in[13];
    const float* ff1_w  = (const float*)d_in[14];
    const float* ff1_b  = (const float*)d_in[15];
    const float* ff2_w  = (const float*)d_in[16];
    const float* ff2_b  = (const float*)d_in[17];
    const float* ln2_g  = (const float*)d_in[18];
    const float* ln2_b  = (const float*)d_in[19];
    const float* c1_w   = (const float*)d_in[20];
    const float* c1_b   = (const float*)d_in[21];
    const float* c2_w   = (const float*)d_in[22];
    const float* c2_b   = (const float*)d_in[23];
    const float* c3_w   = (const float*)d_in[24];
    const float* c3_b   = (const float*)d_in[25];
    float* ws  = (float*)d_ws;
    float* out = (float*)d_out;

    float* cwT    = ws + OFF_CWT;
    float* Wpack  = ws + OFF_WPACK;
    float* TmatT  = ws + OFF_TMATT;
    float* bR     = ws + OFF_BR;
    float* WcatT  = ws + OFF_WCATT;
    float* bprime = ws + OFF_BPRIME;

    hipLaunchKernelGGL(prep0_kernel, dim3(198), dim3(256), 0, stream,
                       chem_w, ff1_w, ff1_b, ff2_w, c1_w, lin2_w, lin1_b, lin2_b,
                       cwT, Wpack, TmatT, bR);
    hipLaunchKernelGGL(prep1_kernel, dim3(371), dim3(256), 0, stream,
                       lin1_w, c1_w, c1_b, TmatT, bR, WcatT, bprime);
    hipLaunchKernelGGL(main_kernel, dim3(BB), dim3(1024), 0, stream,
                       drug, pos_w, cwT, Wpack, qkv_w, qkv_b, out_w, out_b,
                       ln1_g, ln1_b, ff2_b, ln2_g, ln2_b,
                       rna, WcatT, bprime, c2_w, c2_b, c3_w, c3_b, out);
}

// Round 5
// 622.047 us; speedup vs baseline: 1.7410x; 1.2509x over previous
//
#include <hip/hip_runtime.h>

#define BB 512
#define LDIM 2713
#define ZDIM 58
#define GDIM 8
#define NLAYER 6
#define FFDIM 2048
#define RNAIN 1018
#define CATDIM 528
#define NCAT 1482    // 1018 rna-folded + 464 flat

typedef float v2f __attribute__((ext_vector_type(2)));
typedef float f32x4 __attribute__((ext_vector_type(4)));
typedef _Float16 f16x4 __attribute__((ext_vector_type(4)));

// ---------------- ws layout (floats) ----------------
#define OFF_CWT    0                    // cwT   [2713][8]          21704
#define OFF_TMATT  21704                // TmatT [256][64]          16384
#define OFF_BR     38088                // bR    [64]               64
#define OFF_WCATT  38152                // WcatT [1482][64]         94848
#define OFF_BPRIME 133000               // bprime[64]               64
#define OFF_W1H    133064               // W1 A-frags f16 [6][128][32][4] = 98304 halves (49152 f)
#define OFF_A2H    182216               // W2 A-frags f16 [6][128][32][4] = 98304 halves (49152 f)
                                        // total 231368 floats (~0.93 MB)

// ============ prep0: cwT transpose + f16 MFMA fragment packs + TmatT + bR ============
__global__ void prep0_kernel(const float* __restrict__ chem_w,
                             const float* __restrict__ ff1_w, const float* __restrict__ ff2_w,
                             const float* __restrict__ c1_w, const float* __restrict__ lin2_w,
                             const float* __restrict__ lin1_b, const float* __restrict__ lin2_b,
                             float* __restrict__ ws) {
    int tid = blockIdx.x * 256 + threadIdx.x;
    float* cwT   = ws + OFF_CWT;
    float* TmatT = ws + OFF_TMATT;
    float* bR    = ws + OFF_BR;
    _Float16* w1hp = (_Float16*)(ws + OFF_W1H);
    _Float16* a2hp = (_Float16*)(ws + OFF_A2H);

    if (tid < 21704) {                       // cwT[l][g] = chem_w[g][l]
        int l = tid >> 3, g = tid & 7;
        cwT[tid] = chem_w[g * LDIM + l];
        return;
    }
    int r1 = tid - 21704;                    // W1 A-frag: A[m=f_local=i][k=g=q*4+j]
    if (r1 < NLAYER * 128 * 32) {
        int li = r1 / 4096, rem = r1 % 4096;
        int ft = rem >> 5, l32 = rem & 31;
        int q = l32 >> 4, i = l32 & 15;
        const float* src = ff1_w + ((size_t)li * FFDIM + ft * 16 + i) * 8 + q * 4;
        size_t dst = ((size_t)(li * 128 + ft) * 32 + l32) * 4;
        #pragma unroll
        for (int j = 0; j < 4; ++j) w1hp[dst + j] = (_Float16)src[j];
        return;
    }
    int r2 = r1 - NLAYER * 128 * 32;         // W2 A-frag: A[m=g=i2][k=f=ft*16+q*4+j]
    if (r2 < NLAYER * 128 * 32) {
        int li = r2 / 4096, rem = r2 % 4096;
        int ft = rem >> 5, s = rem & 31;
        int q = s >> 3, i2 = s & 7;
        const float* src = ff2_w + ((size_t)li * GDIM + i2) * FFDIM + ft * 16 + q * 4;
        size_t dst = ((size_t)(li * 128 + ft) * 32 + s) * 4;
        #pragma unroll
        for (int j = 0; j < 4; ++j) a2hp[dst + j] = (_Float16)src[j];
        return;
    }
    int r3 = r2 - NLAYER * 128 * 32;         // TmatT[n][j] = sum_m c1[j][m]*lin2[m][n]
    if (r3 < 256 * 64) {
        int n = r3 >> 6, j = r3 & 63;
        float a = 0.f;
        for (int m = 0; m < 64; ++m) a += c1_w[j * CATDIM + m] * lin2_w[m * 256 + n];
        TmatT[r3] = a;
        return;
    }
    int r4 = r3 - 256 * 64;                  // bR[m] = lin2_b[m] + sum_n lin2[m][n]*lin1_b[n]
    if (r4 < 64) {
        float a = lin2_b[r4];
        for (int n = 0; n < 256; ++n) a += lin2_w[r4 * 256 + n] * lin1_b[n];
        bR[r4] = a;
    }
}

// ============ prep1: WcatT rows + bprime ============
__global__ void prep1_kernel(const float* __restrict__ lin1_w, const float* __restrict__ c1_w,
                             const float* __restrict__ c1_b, const float* __restrict__ ws_in,
                             float* __restrict__ ws) {
    int tid = blockIdx.x * 256 + threadIdx.x;
    const float* TmatT = ws_in + OFF_TMATT;
    const float* bR    = ws_in + OFF_BR;
    float* WcatT  = ws + OFF_WCATT;
    float* bprime = ws + OFF_BPRIME;
    if (tid < RNAIN * 64) {                  // WcatT[k][j] = sum_n TmatT[n][j]*lin1_w[n][k]
        int k = tid >> 6, j = tid & 63;
        float a = 0.f;
        #pragma unroll 4
        for (int n = 0; n < 256; ++n) a += TmatT[n * 64 + j] * lin1_w[n * RNAIN + k];
        WcatT[tid] = a;
        return;
    }
    int q = tid - RNAIN * 64;                // WcatT[1018+kk][j] = c1_w[j][64+kk]
    if (q < 464 * 64) {
        int kk = q >> 6, j = q & 63;
        WcatT[(RNAIN + kk) * 64 + j] = c1_w[j * CATDIM + 64 + kk];
        return;
    }
    int j = q - 464 * 64;                    // bprime[j] = c1_b[j] + sum_m c1[j][m]*bR[m]
    if (j < 64) {
        float a = c1_b[j];
        for (int m = 0; m < 64; ++m) a += c1_w[j * CATDIM + m] * bR[m];
        bprime[j] = a;
    }
}

// ============ fused main: embed -> 6 layers (MFMA FFN) -> head ============
__global__ __launch_bounds__(1024, 4) void main_kernel(
    const float* __restrict__ drug, const float* __restrict__ pos_w,
    const float* __restrict__ cwT,
    const _Float16* __restrict__ w1h, const _Float16* __restrict__ a2h,
    const float* __restrict__ ff1_b,
    const float* __restrict__ qkv_w, const float* __restrict__ qkv_b,
    const float* __restrict__ out_w, const float* __restrict__ out_b,
    const float* __restrict__ ln1_g, const float* __restrict__ ln1_b,
    const float* __restrict__ ff2_b,
    const float* __restrict__ ln2_g, const float* __restrict__ ln2_b,
    const float* __restrict__ rna, const float* __restrict__ WcatT,
    const float* __restrict__ bprime,
    const float* __restrict__ c2_w, const float* __restrict__ c2_b,
    const float* __restrict__ c3_w, const float* __restrict__ c3_b,
    float* __restrict__ out) {
    __shared__ float smem[12712];
    float* xs    = smem;            // 512  (64 z-rows padded x 8)
    float* qs    = smem + 512;      // 480  [h][60]
    float* ks    = smem + 992;      // 480
    float* vs    = smem + 1472;     // 480
    float* os    = smem + 1952;     // 512  [s][h]
    float* part  = smem + 2464;     // 8192 [w16][64][8]
    float* qkvws = smem + 10656;    // 1152
    float* qkvbs = smem + 11808;    // 144
    float* outws = smem + 11952;    // 384
    float* outbs = smem + 12336;    // 48
    float* l1gs  = smem + 12384;    // 48
    float* l1bs  = smem + 12432;    // 48
    float* l2gs  = smem + 12480;    // 48
    float* l2bs  = smem + 12528;    // 48
    float* f2bs  = smem + 12576;    // 48
    float* h1s   = smem + 12624;    // 64
    float* h2s   = smem + 12688;    // 8

    const int b = blockIdx.x;
    const int t = threadIdx.x;
    const int w = __builtin_amdgcn_readfirstlane(t >> 6);   // wave id 0..15
    const int lane = t & 63;
    const int quad = lane >> 4;
    const int i16 = lane & 15;

    // ---- hoist small per-layer weights ----
    for (int i = t; i < 1152; i += 1024) qkvws[i] = qkv_w[i];
    if (t < 144) qkvbs[t] = qkv_b[t];
    if (t < 384) outws[t] = out_w[t];
    if (t < 48) {
        outbs[t] = out_b[t];
        l1gs[t] = ln1_g[t]; l1bs[t] = ln1_b[t];
        l2gs[t] = ln2_g[t]; l2bs[t] = ln2_b[t];
        f2bs[t] = ff2_b[t];
    }

    // ---- embed: wave w covers l-slice (170), lane = z ----
    {
        int z = (lane < ZDIM) ? lane : (ZDIM - 1);
        const float* dp = drug + (size_t)b * (LDIM * ZDIM);
        v2f a0 = {0.f, 0.f}, a1 = {0.f, 0.f}, a2 = {0.f, 0.f}, a3 = {0.f, 0.f};
        int l0 = w * 170;
        int l1 = (l0 + 170 < LDIM) ? (l0 + 170) : LDIM;
        int l = l0;
        for (; l + 8 <= l1; l += 8) {
            float d[8];
            #pragma unroll
            for (int ii = 0; ii < 8; ++ii) d[ii] = dp[(l + ii) * ZDIM + z];
            #pragma unroll
            for (int ii = 0; ii < 8; ++ii) {
                const v2f* cw = (const v2f*)(cwT + (l + ii) * 8);
                v2f dd = {d[ii], d[ii]};
                a0 += cw[0] * dd; a1 += cw[1] * dd; a2 += cw[2] * dd; a3 += cw[3] * dd;
            }
        }
        for (; l < l1; ++l) {
            float d = dp[l * ZDIM + z];
            const v2f* cw = (const v2f*)(cwT + l * 8);
            v2f dd = {d, d};
            a0 += cw[0] * dd; a1 += cw[1] * dd; a2 += cw[2] * dd; a3 += cw[3] * dd;
        }
        v2f* pr = (v2f*)(part + (w * 64 + lane) * 8);
        pr[0] = a0; pr[1] = a1; pr[2] = a2; pr[3] = a3;
    }
    __syncthreads();
    if (t < 512) {
        if (t < 464) {
            int z = t >> 3, g = t & 7;
            float s = 0.f;
            #pragma unroll
            for (int ww = 0; ww < 16; ++ww) s += part[(ww * 64 + z) * 8 + g];
            xs[t] = s + pos_w[g * ZDIM + z];
        } else {
            xs[t] = 0.f;   // zero pad rows z=58..63
        }
    }
    __syncthreads();

    // ---- 6 transformer layers ----
    for (int li = 0; li < NLAYER; ++li) {
        // qkv projection: thread = (z, h)
        if (t < 464) {
            int z = t >> 3, h = t & 7;
            const float4* xr = (const float4*)(xs + z * 8);
            float4 x0 = xr[0], x1 = xr[1];
            #pragma unroll
            for (int p = 0; p < 3; ++p) {
                int j = p * 8 + h;
                const float4* wr = (const float4*)(qkvws + li * 192 + j * 8);
                float4 w0 = wr[0], w1 = wr[1];
                float a = qkvbs[li * 24 + j]
                        + x0.x * w0.x + x0.y * w0.y + x0.z * w0.z + x0.w * w0.w
                        + x1.x * w1.x + x1.y * w1.y + x1.z * w1.z + x1.w * w1.w;
                float* dst = (p == 0) ? qs : (p == 1) ? ks : vs;
                dst[h * 60 + z] = a;
            }
        }
        __syncthreads();

        // attention (HD=1 rank-1 logits, LN'd activations -> unshifted softmax exact)
        if (t < 464) {
            int h = t & 7, s = t >> 3;
            float q = qs[h * 60 + s];
            const float4* kr = (const float4*)(ks + h * 60);
            const float4* vr = (const float4*)(vs + h * 60);
            float sum = 0.f, oa = 0.f;
            #pragma unroll 2
            for (int c = 0; c < 14; ++c) {
                float4 k4 = kr[c], v4 = vr[c];
                float e0 = __expf(q * k4.x); sum += e0; oa += e0 * v4.x;
                float e1 = __expf(q * k4.y); sum += e1; oa += e1 * v4.y;
                float e2 = __expf(q * k4.z); sum += e2; oa += e2 * v4.z;
                float e3 = __expf(q * k4.w); sum += e3; oa += e3 * v4.w;
            }
            {
                const float* kk = ks + h * 60;
                const float* vv = vs + h * 60;
                float e0 = __expf(q * kk[56]); sum += e0; oa += e0 * vv[56];
                float e1 = __expf(q * kk[57]); sum += e1; oa += e1 * vv[57];
            }
            os[t] = oa / sum;
        }
        __syncthreads();

        // out-proj + residual + LN1
        if (t < 464) {
            int z = t >> 3, g = t & 7;
            const float4* orow = (const float4*)(os + z * 8);
            float4 o0 = orow[0], o1 = orow[1];
            const float4* wr = (const float4*)(outws + li * 64 + g * 8);
            float4 w0 = wr[0], w1 = wr[1];
            float a = outbs[li * 8 + g] + xs[t]
                    + o0.x * w0.x + o0.y * w0.y + o0.z * w0.z + o0.w * w0.w
                    + o1.x * w1.x + o1.y * w1.y + o1.z * w1.z + o1.w * w1.w;
            float s8 = a + __shfl_xor(a, 1);
            s8 += __shfl_xor(s8, 2);
            s8 += __shfl_xor(s8, 4);
            float mu = s8 * 0.125f;
            float d = a - mu;
            float vv = d * d;
            vv += __shfl_xor(vv, 1); vv += __shfl_xor(vv, 2); vv += __shfl_xor(vv, 4);
            float inv = rsqrtf(vv * 0.125f + 1e-5f);
            xs[t] = d * inv * l1gs[li * 8 + g] + l1bs[li * 8 + g];
        }
        __syncthreads();

        // ---- FFN via MFMA f16: wave w owns f-slice [w*128, (w+1)*128) ----
        // FFN1: D[m=f][n=z] = W1frag x xfrag (K=16, g 0..7 real, quads 2-3 zero)
        // H C-layout == B-operand layout for K=16 -> feeds FFN2 directly, no shuffle.
        {
            // x B-frags per z-tile (quads 0,1 hold g 0..3 / 4..7; quads 2,3 zero)
            f16x4 xb[4];
            #pragma unroll
            for (int nt = 0; nt < 4; ++nt) {
                if (quad < 2) {
                    const float4* xp = (const float4*)(xs + (nt * 16 + i16) * 8 + quad * 4);
                    float4 xv = *xp;
                    xb[nt][0] = (_Float16)xv.x; xb[nt][1] = (_Float16)xv.y;
                    xb[nt][2] = (_Float16)xv.z; xb[nt][3] = (_Float16)xv.w;
                } else {
                    xb[nt][0] = (_Float16)0.f; xb[nt][1] = (_Float16)0.f;
                    xb[nt][2] = (_Float16)0.f; xb[nt][3] = (_Float16)0.f;
                }
            }
            f32x4 oacc[4];
            #pragma unroll
            for (int nt = 0; nt < 4; ++nt) { oacc[nt][0]=0.f; oacc[nt][1]=0.f; oacc[nt][2]=0.f; oacc[nt][3]=0.f; }

            const _Float16* w1p = w1h + ((size_t)(li * 128 + w * 8) * 32) * 4;
            const _Float16* a2p = a2h + ((size_t)(li * 128 + w * 8) * 32) * 4;
            const float* b1p = ff1_b + li * FFDIM + w * 128;

            #pragma unroll 2
            for (int ft = 0; ft < 8; ++ft) {
                f16x4 w1f = {};
                if (lane < 32) w1f = *(const f16x4*)(w1p + (size_t)(ft * 32 + lane) * 4);
                f16x4 a2f = {};
                if (i16 < 8) a2f = *(const f16x4*)(a2p + (size_t)(ft * 32 + quad * 8 + i16) * 4);
                f32x4 b1v = *(const f32x4*)(b1p + ft * 16 + quad * 4);  // bias row = quad*4+reg
                #pragma unroll
                for (int nt = 0; nt < 4; ++nt) {
                    f32x4 h = b1v;
                    h = __builtin_amdgcn_mfma_f32_16x16x16f16(w1f, xb[nt], h, 0, 0, 0);
                    h[0] = fmaxf(h[0], 0.f); h[1] = fmaxf(h[1], 0.f);
                    h[2] = fmaxf(h[2], 0.f); h[3] = fmaxf(h[3], 0.f);
                    f16x4 hb;
                    hb[0] = (_Float16)h[0]; hb[1] = (_Float16)h[1];
                    hb[2] = (_Float16)h[2]; hb[3] = (_Float16)h[3];
                    oacc[nt] = __builtin_amdgcn_mfma_f32_16x16x16f16(a2f, hb, oacc[nt], 0, 0, 0);
                }
            }
            // write per-wave partials: lane(q<2,i): out[g=q*4+reg][z=nt*16+i]
            if (quad < 2) {
                #pragma unroll
                for (int nt = 0; nt < 4; ++nt) {
                    float4 o4 = make_float4(oacc[nt][0], oacc[nt][1], oacc[nt][2], oacc[nt][3]);
                    *(float4*)(part + ((w * 64 + nt * 16 + i16) * 8 + quad * 4)) = o4;
                }
            }
        }
        __syncthreads();

        // reduce partials + residual + LN2
        if (t < 464) {
            int z = t >> 3, g = t & 7;
            float s = 0.f;
            #pragma unroll
            for (int ww = 0; ww < 16; ++ww) s += part[(ww * 64 + z) * 8 + g];
            float a = xs[t] + s + f2bs[li * 8 + g];
            float s8 = a + __shfl_xor(a, 1);
            s8 += __shfl_xor(s8, 2);
            s8 += __shfl_xor(s8, 4);
            float mu = s8 * 0.125f;
            float d = a - mu;
            float vv = d * d;
            vv += __shfl_xor(vv, 1); vv += __shfl_xor(vv, 2); vv += __shfl_xor(vv, 4);
            float inv = rsqrtf(vv * 0.125f + 1e-5f);
            xs[t] = d * inv * l2gs[li * 8 + g] + l2bs[li * 8 + g];
        }
        __syncthreads();
    }

    // ---- head ----
    {
        float* cat = part;               // [0..1017]
        float* partial = part + 4096;    // [16][64]
        const float* rg = rna + (size_t)b * RNAIN;
        for (int i = t; i < RNAIN; i += 1024) cat[i] = rg[i];
        __syncthreads();
        int j = lane;
        int k0 = w * 93;
        int k1 = (k0 + 93 < NCAT) ? (k0 + 93) : NCAT;
        float a = (w == 0) ? bprime[j] : 0.f;
        #pragma unroll 4
        for (int k = k0; k < k1; ++k) {
            float ck = (k < RNAIN) ? cat[k] : xs[k - RNAIN];
            a += ck * WcatT[k * 64 + j];
        }
        partial[w * 64 + j] = a;
        __syncthreads();
        if (t < 64) {
            float s = 0.f;
            #pragma unroll
            for (int ww = 0; ww < 16; ++ww) s += partial[ww * 64 + t];
            h1s[t] = s;
        }
    }
    __syncthreads();
    if (t < 8) {
        float a2 = c2_b[t];
        #pragma unroll 8
        for (int m = 0; m < 64; ++m) a2 += h1s[m] * c2_w[t * 64 + m];
        h2s[t] = a2;
    }
    __syncthreads();
    if (t == 0) {
        float a3 = c3_b[0];
        #pragma unroll
        for (int jj = 0; jj < 8; ++jj) a3 += h2s[jj] * c3_w[jj];
        out[b] = a3;
    }
}

extern "C" void kernel_launch(void* const* d_in, const int* in_sizes, int n_in,
                              void* d_out, int out_size, void* d_ws, size_t ws_size,
                              hipStream_t stream) {
    const float* rna    = (const float*)d_in[0];
    const float* drug   = (const float*)d_in[1];
    const float* lin1_w = (const float*)d_in[2];
    const float* lin1_b = (const float*)d_in[3];
    const float* lin2_w = (const float*)d_in[4];
    const float* lin2_b = (const float*)d_in[5];
    const float* chem_w = (const float*)d_in[6];
    const float* pos_w  = (const float*)d_in[7];
    const float* qkv_w  = (const float*)d_in[8];
    const float* qkv_b  = (const float*)d_in[9];
    const float* out_w  = (const float*)d_in[10];
    const float* out_b  = (const float*)d_in[11];
    const float* ln1_g  = (const float*)d_in[12];
    const float* ln1_b  = (const float*)d_in[13];
    const float* ff1_w  = (const float*)d_in[14];
    const float* ff1_b  = (const float*)d_in[15];
    const float* ff2_w  = (const float*)d_in[16];
    const float* ff2_b  = (const float*)d_in[17];
    const float* ln2_g  = (const float*)d_in[18];
    const float* ln2_b  = (const float*)d_in[19];
    const float* c1_w   = (const float*)d_in[20];
    const float* c1_b   = (const float*)d_in[21];
    const float* c2_w   = (const float*)d_in[22];
    const float* c2_b   = (const float*)d_in[23];
    const float* c3_w   = (const float*)d_in[24];
    const float* c3_b   = (const float*)d_in[25];
    float* ws  = (float*)d_ws;
    float* out = (float*)d_out;

    const float* cwT      = ws + OFF_CWT;
    const _Float16* w1h   = (const _Float16*)(ws + OFF_W1H);
    const _Float16* a2h   = (const _Float16*)(ws + OFF_A2H);
    const float* WcatT    = ws + OFF_WCATT;
    const float* bprime   = ws + OFF_BPRIME;

    hipLaunchKernelGGL(prep0_kernel, dim3(342), dim3(256), 0, stream,
                       chem_w, ff1_w, ff2_w, c1_w, lin2_w, lin1_b, lin2_b, ws);
    hipLaunchKernelGGL(prep1_kernel, dim3(371), dim3(256), 0, stream,
                       lin1_w, c1_w, c1_b, ws, ws);
    hipLaunchKernelGGL(main_kernel, dim3(BB), dim3(1024), 0, stream,
                       drug, pos_w, cwT, w1h, a2h, ff1_b,
                       qkv_w, qkv_b, out_w, out_b,
                       ln1_g, ln1_b, ff2_b, ln2_g, ln2_b,
                       rna, WcatT, bprime, c2_w, c2_b, c3_w, c3_b, out);
}

// Round 6
// 609.529 us; speedup vs baseline: 1.7768x; 1.0205x over previous
//
#include <hip/hip_runtime.h>

#define BB 512
#define LDIM 2713
#define ZDIM 58
#define GDIM 8
#define NLAYER 6
#define FFDIM 2048
#define RNAIN 1018
#define CATDIM 528
#define NCAT 1482    // 1018 rna-folded + 464 flat
#define LQ 679       // ceil(2713/4)

typedef float v2f __attribute__((ext_vector_type(2)));
typedef float f32x4 __attribute__((ext_vector_type(4)));
typedef _Float16 f16x4 __attribute__((ext_vector_type(4)));

// ---------------- ws layout (floats) ----------------
#define OFF_TMATT  0                    // TmatT [256][64]          16384
#define OFF_BR     16384                // bR    [64]               64
#define OFF_WCATT  16448                // WcatT [1482][64]         94848
#define OFF_BPRIME 111296               // bprime[64]               64
#define OFF_W1H    111360               // W1 A-frags f16 [6][128][32][4] = 98304 h (49152 f)
#define OFF_A2H    160512               // W2 A-frags f16 [6][128][32][4] = 98304 h (49152 f)
#define OFF_EPART  209664               // epart [512*4][464]       950272
                                        // total 1159936 floats (~4.64 MB)

// ============ embed: block = (b, quarter); chem slice staged in LDS ============
__global__ __launch_bounds__(512, 8) void embed_kernel(
    const float* __restrict__ drug, const float* __restrict__ chem_w,
    float* __restrict__ epart) {
    __shared__ float cwl[LQ * 8 + 8];        // [i][g], i = local l row
    __shared__ float part[8][ZDIM][8];
    const int bq = blockIdx.x;
    const int b = bq >> 2, q = bq & 3;
    const int t = threadIdx.x;
    const int w = t >> 6;
    const int lane = t & 63;
    const int l0 = q * LQ;
    const int nrows = (LDIM - l0 < LQ) ? (LDIM - l0) : LQ;   // 679,679,679,676

    // stage chem slice transposed: cwl[i*8+g] = chem_w[g][l0+i] (coalesced reads)
    #pragma unroll
    for (int g = 0; g < 8; ++g)
        for (int i = t; i < nrows; i += 512)
            cwl[i * 8 + g] = chem_w[g * LDIM + l0 + i];
    __syncthreads();

    {
        int z = (lane < ZDIM) ? lane : (ZDIM - 1);
        const float* dp = drug + (size_t)b * (LDIM * ZDIM) + (size_t)l0 * ZDIM;
        v2f a0 = {0.f, 0.f}, a1 = {0.f, 0.f}, a2 = {0.f, 0.f}, a3 = {0.f, 0.f};
        int r0 = w * 85;
        int r1 = (r0 + 85 < nrows) ? (r0 + 85) : nrows;
        int r = r0;
        for (; r + 4 <= r1; r += 4) {
            float d0 = dp[(r + 0) * ZDIM + z];
            float d1 = dp[(r + 1) * ZDIM + z];
            float d2 = dp[(r + 2) * ZDIM + z];
            float d3 = dp[(r + 3) * ZDIM + z];
            const v2f* c0 = (const v2f*)(cwl + (r + 0) * 8);
            const v2f* c1 = (const v2f*)(cwl + (r + 1) * 8);
            const v2f* c2 = (const v2f*)(cwl + (r + 2) * 8);
            const v2f* c3 = (const v2f*)(cwl + (r + 3) * 8);
            v2f dd;
            dd = (v2f){d0, d0};
            a0 += c0[0] * dd; a1 += c0[1] * dd; a2 += c0[2] * dd; a3 += c0[3] * dd;
            dd = (v2f){d1, d1};
            a0 += c1[0] * dd; a1 += c1[1] * dd; a2 += c1[2] * dd; a3 += c1[3] * dd;
            dd = (v2f){d2, d2};
            a0 += c2[0] * dd; a1 += c2[1] * dd; a2 += c2[2] * dd; a3 += c2[3] * dd;
            dd = (v2f){d3, d3};
            a0 += c3[0] * dd; a1 += c3[1] * dd; a2 += c3[2] * dd; a3 += c3[3] * dd;
        }
        for (; r < r1; ++r) {
            float d = dp[r * ZDIM + z];
            const v2f* cc = (const v2f*)(cwl + r * 8);
            v2f dd = {d, d};
            a0 += cc[0] * dd; a1 += cc[1] * dd; a2 += cc[2] * dd; a3 += cc[3] * dd;
        }
        if (lane < ZDIM) {
            v2f* pr = (v2f*)(&part[w][z][0]);
            pr[0] = a0; pr[1] = a1; pr[2] = a2; pr[3] = a3;
        }
    }
    __syncthreads();
    if (t < 464) {
        int z = t >> 3, g = t & 7;
        float s = 0.f;
        #pragma unroll
        for (int ww = 0; ww < 8; ++ww) s += part[ww][z][g];
        epart[(size_t)bq * 464 + t] = s;
    }
}

// ============ prep0: f16 MFMA fragment packs + TmatT + bR ============
__global__ void prep0_kernel(const float* __restrict__ ff1_w, const float* __restrict__ ff2_w,
                             const float* __restrict__ c1_w, const float* __restrict__ lin2_w,
                             const float* __restrict__ lin1_b, const float* __restrict__ lin2_b,
                             float* __restrict__ ws) {
    int tid = blockIdx.x * 256 + threadIdx.x;
    float* TmatT = ws + OFF_TMATT;
    float* bR    = ws + OFF_BR;
    _Float16* w1hp = (_Float16*)(ws + OFF_W1H);
    _Float16* a2hp = (_Float16*)(ws + OFF_A2H);

    int r1 = tid;                            // W1 A-frag: A[m=f_local=i][k=g=q*4+j]
    if (r1 < NLAYER * 128 * 32) {
        int li = r1 / 4096, rem = r1 % 4096;
        int ft = rem >> 5, l32 = rem & 31;
        int q = l32 >> 4, i = l32 & 15;
        const float* src = ff1_w + ((size_t)li * FFDIM + ft * 16 + i) * 8 + q * 4;
        size_t dst = ((size_t)(li * 128 + ft) * 32 + l32) * 4;
        #pragma unroll
        for (int j = 0; j < 4; ++j) w1hp[dst + j] = (_Float16)src[j];
        return;
    }
    int r2 = r1 - NLAYER * 128 * 32;         // W2 A-frag: A[m=g=i2][k=f=ft*16+q*4+j]
    if (r2 < NLAYER * 128 * 32) {
        int li = r2 / 4096, rem = r2 % 4096;
        int ft = rem >> 5, s = rem & 31;
        int q = s >> 3, i2 = s & 7;
        const float* src = ff2_w + ((size_t)li * GDIM + i2) * FFDIM + ft * 16 + q * 4;
        size_t dst = ((size_t)(li * 128 + ft) * 32 + s) * 4;
        #pragma unroll
        for (int j = 0; j < 4; ++j) a2hp[dst + j] = (_Float16)src[j];
        return;
    }
    int r3 = r2 - NLAYER * 128 * 32;         // TmatT[n][j] = sum_m c1[j][m]*lin2[m][n]
    if (r3 < 256 * 64) {
        int n = r3 >> 6, j = r3 & 63;
        float a = 0.f;
        for (int m = 0; m < 64; ++m) a += c1_w[j * CATDIM + m] * lin2_w[m * 256 + n];
        TmatT[r3] = a;
        return;
    }
    int r4 = r3 - 256 * 64;                  // bR[m] = lin2_b[m] + sum_n lin2[m][n]*lin1_b[n]
    if (r4 < 64) {
        float a = lin2_b[r4];
        for (int n = 0; n < 256; ++n) a += lin2_w[r4 * 256 + n] * lin1_b[n];
        bR[r4] = a;
    }
}

// ============ prep1: WcatT rows + bprime ============
__global__ void prep1_kernel(const float* __restrict__ lin1_w, const float* __restrict__ c1_w,
                             const float* __restrict__ c1_b, float* __restrict__ ws) {
    int tid = blockIdx.x * 256 + threadIdx.x;
    const float* TmatT = ws + OFF_TMATT;
    const float* bR    = ws + OFF_BR;
    float* WcatT  = ws + OFF_WCATT;
    float* bprime = ws + OFF_BPRIME;
    if (tid < RNAIN * 64) {                  // WcatT[k][j] = sum_n TmatT[n][j]*lin1_w[n][k]
        int k = tid >> 6, j = tid & 63;
        float a = 0.f;
        #pragma unroll 4
        for (int n = 0; n < 256; ++n) a += TmatT[n * 64 + j] * lin1_w[n * RNAIN + k];
        WcatT[tid] = a;
        return;
    }
    int q = tid - RNAIN * 64;                // WcatT[1018+kk][j] = c1_w[j][64+kk]
    if (q < 464 * 64) {
        int kk = q >> 6, j = q & 63;
        WcatT[(RNAIN + kk) * 64 + j] = c1_w[j * CATDIM + 64 + kk];
        return;
    }
    int j = q - 464 * 64;                    // bprime[j] = c1_b[j] + sum_m c1[j][m]*bR[m]
    if (j < 64) {
        float a = c1_b[j];
        for (int m = 0; m < 64; ++m) a += c1_w[j * CATDIM + m] * bR[m];
        bprime[j] = a;
    }
}

// ============ fused main: reduce epart -> 6 layers (MFMA FFN) -> head ============
__global__ __launch_bounds__(1024, 8) void main_kernel(
    const float* __restrict__ epart, const float* __restrict__ pos_w,
    const _Float16* __restrict__ w1h, const _Float16* __restrict__ a2h,
    const float* __restrict__ ff1_b,
    const float* __restrict__ qkv_w, const float* __restrict__ qkv_b,
    const float* __restrict__ out_w, const float* __restrict__ out_b,
    const float* __restrict__ ln1_g, const float* __restrict__ ln1_b,
    const float* __restrict__ ff2_b,
    const float* __restrict__ ln2_g, const float* __restrict__ ln2_b,
    const float* __restrict__ rna, const float* __restrict__ WcatT,
    const float* __restrict__ bprime,
    const float* __restrict__ c2_w, const float* __restrict__ c2_b,
    const float* __restrict__ c3_w, const float* __restrict__ c3_b,
    float* __restrict__ out) {
    __shared__ float smem[12712];
    float* xs    = smem;            // 512  (64 z-rows padded x 8)
    float* qs    = smem + 512;      // 480  [h][60]
    float* ks    = smem + 992;      // 480
    float* vs    = smem + 1472;     // 480
    float* os    = smem + 1952;     // 512  [s][h]
    float* part  = smem + 2464;     // 8192 [w16][64][8]
    float* qkvws = smem + 10656;    // 1152
    float* qkvbs = smem + 11808;    // 144
    float* outws = smem + 11952;    // 384
    float* outbs = smem + 12336;    // 48
    float* l1gs  = smem + 12384;    // 48
    float* l1bs  = smem + 12432;    // 48
    float* l2gs  = smem + 12480;    // 48
    float* l2bs  = smem + 12528;    // 48
    float* f2bs  = smem + 12576;    // 48
    float* h1s   = smem + 12624;    // 64
    float* h2s   = smem + 12688;    // 8

    const int b = blockIdx.x;
    const int t = threadIdx.x;
    const int w = __builtin_amdgcn_readfirstlane(t >> 6);   // wave id 0..15
    const int lane = t & 63;
    const int quad = lane >> 4;
    const int i16 = lane & 15;

    // ---- hoist small per-layer weights ----
    for (int i = t; i < 1152; i += 1024) qkvws[i] = qkv_w[i];
    if (t < 144) qkvbs[t] = qkv_b[t];
    if (t < 384) outws[t] = out_w[t];
    if (t < 48) {
        outbs[t] = out_b[t];
        l1gs[t] = ln1_g[t]; l1bs[t] = ln1_b[t];
        l2gs[t] = ln2_g[t]; l2bs[t] = ln2_b[t];
        f2bs[t] = ff2_b[t];
    }

    // ---- reduce embed partials + pos ----
    if (t < 512) {
        if (t < 464) {
            int z = t >> 3, g = t & 7;
            const float* ep = epart + (size_t)(b * 4) * 464 + t;
            float s = ep[0] + ep[464] + ep[928] + ep[1392] + pos_w[g * ZDIM + z];
            xs[t] = s;
        } else {
            xs[t] = 0.f;   // zero pad rows z=58..63
        }
    }
    __syncthreads();

    // ---- 6 transformer layers ----
    for (int li = 0; li < NLAYER; ++li) {
        // qkv projection: thread = (z, h)
        if (t < 464) {
            int z = t >> 3, h = t & 7;
            const float4* xr = (const float4*)(xs + z * 8);
            float4 x0 = xr[0], x1 = xr[1];
            #pragma unroll
            for (int p = 0; p < 3; ++p) {
                int j = p * 8 + h;
                const float4* wr = (const float4*)(qkvws + li * 192 + j * 8);
                float4 w0 = wr[0], w1 = wr[1];
                float a = qkvbs[li * 24 + j]
                        + x0.x * w0.x + x0.y * w0.y + x0.z * w0.z + x0.w * w0.w
                        + x1.x * w1.x + x1.y * w1.y + x1.z * w1.z + x1.w * w1.w;
                float* dst = (p == 0) ? qs : (p == 1) ? ks : vs;
                dst[h * 60 + z] = a;
            }
        }
        __syncthreads();

        // attention (HD=1 rank-1 logits, LN'd activations -> unshifted softmax exact)
        if (t < 464) {
            int h = t & 7, s = t >> 3;
            float q = qs[h * 60 + s];
            const float4* kr = (const float4*)(ks + h * 60);
            const float4* vr = (const float4*)(vs + h * 60);
            float sum = 0.f, oa = 0.f;
            #pragma unroll 2
            for (int c = 0; c < 14; ++c) {
                float4 k4 = kr[c], v4 = vr[c];
                float e0 = __expf(q * k4.x); sum += e0; oa += e0 * v4.x;
                float e1 = __expf(q * k4.y); sum += e1; oa += e1 * v4.y;
                float e2 = __expf(q * k4.z); sum += e2; oa += e2 * v4.z;
                float e3 = __expf(q * k4.w); sum += e3; oa += e3 * v4.w;
            }
            {
                const float* kk = ks + h * 60;
                const float* vv = vs + h * 60;
                float e0 = __expf(q * kk[56]); sum += e0; oa += e0 * vv[56];
                float e1 = __expf(q * kk[57]); sum += e1; oa += e1 * vv[57];
            }
            os[t] = oa / sum;
        }
        __syncthreads();

        // out-proj + residual + LN1
        if (t < 464) {
            int z = t >> 3, g = t & 7;
            const float4* orow = (const float4*)(os + z * 8);
            float4 o0 = orow[0], o1 = orow[1];
            const float4* wr = (const float4*)(outws + li * 64 + g * 8);
            float4 w0 = wr[0], w1 = wr[1];
            float a = outbs[li * 8 + g] + xs[t]
                    + o0.x * w0.x + o0.y * w0.y + o0.z * w0.z + o0.w * w0.w
                    + o1.x * w1.x + o1.y * w1.y + o1.z * w1.z + o1.w * w1.w;
            float s8 = a + __shfl_xor(a, 1);
            s8 += __shfl_xor(s8, 2);
            s8 += __shfl_xor(s8, 4);
            float mu = s8 * 0.125f;
            float d = a - mu;
            float vv = d * d;
            vv += __shfl_xor(vv, 1); vv += __shfl_xor(vv, 2); vv += __shfl_xor(vv, 4);
            float inv = rsqrtf(vv * 0.125f + 1e-5f);
            xs[t] = d * inv * l1gs[li * 8 + g] + l1bs[li * 8 + g];
        }
        __syncthreads();

        // ---- FFN via MFMA f16: wave w owns f-slice [w*128, (w+1)*128) ----
        {
            f16x4 xb[4];
            #pragma unroll
            for (int nt = 0; nt < 4; ++nt) {
                if (quad < 2) {
                    const float4* xp = (const float4*)(xs + (nt * 16 + i16) * 8 + quad * 4);
                    float4 xv = *xp;
                    xb[nt][0] = (_Float16)xv.x; xb[nt][1] = (_Float16)xv.y;
                    xb[nt][2] = (_Float16)xv.z; xb[nt][3] = (_Float16)xv.w;
                } else {
                    xb[nt][0] = (_Float16)0.f; xb[nt][1] = (_Float16)0.f;
                    xb[nt][2] = (_Float16)0.f; xb[nt][3] = (_Float16)0.f;
                }
            }
            f32x4 oacc[4];
            #pragma unroll
            for (int nt = 0; nt < 4; ++nt) { oacc[nt][0]=0.f; oacc[nt][1]=0.f; oacc[nt][2]=0.f; oacc[nt][3]=0.f; }

            const _Float16* w1p = w1h + ((size_t)(li * 128 + w * 8) * 32) * 4;
            const _Float16* a2p = a2h + ((size_t)(li * 128 + w * 8) * 32) * 4;
            const float* b1p = ff1_b + li * FFDIM + w * 128;

            #pragma unroll 2
            for (int ft = 0; ft < 8; ++ft) {
                f16x4 w1f = {};
                if (lane < 32) w1f = *(const f16x4*)(w1p + (size_t)(ft * 32 + lane) * 4);
                f16x4 a2f = {};
                if (i16 < 8) a2f = *(const f16x4*)(a2p + (size_t)(ft * 32 + quad * 8 + i16) * 4);
                f32x4 b1v = *(const f32x4*)(b1p + ft * 16 + quad * 4);
                #pragma unroll
                for (int nt = 0; nt < 4; ++nt) {
                    f32x4 h = b1v;
                    h = __builtin_amdgcn_mfma_f32_16x16x16f16(w1f, xb[nt], h, 0, 0, 0);
                    h[0] = fmaxf(h[0], 0.f); h[1] = fmaxf(h[1], 0.f);
                    h[2] = fmaxf(h[2], 0.f); h[3] = fmaxf(h[3], 0.f);
                    f16x4 hb;
                    hb[0] = (_Float16)h[0]; hb[1] = (_Float16)h[1];
                    hb[2] = (_Float16)h[2]; hb[3] = (_Float16)h[3];
                    oacc[nt] = __builtin_amdgcn_mfma_f32_16x16x16f16(a2f, hb, oacc[nt], 0, 0, 0);
                }
            }
            if (quad < 2) {
                #pragma unroll
                for (int nt = 0; nt < 4; ++nt) {
                    float4 o4 = make_float4(oacc[nt][0], oacc[nt][1], oacc[nt][2], oacc[nt][3]);
                    *(float4*)(part + ((w * 64 + nt * 16 + i16) * 8 + quad * 4)) = o4;
                }
            }
        }
        __syncthreads();

        // reduce partials + residual + LN2
        if (t < 464) {
            int z = t >> 3, g = t & 7;
            float s = 0.f;
            #pragma unroll
            for (int ww = 0; ww < 16; ++ww) s += part[(ww * 64 + z) * 8 + g];
            float a = xs[t] + s + f2bs[li * 8 + g];
            float s8 = a + __shfl_xor(a, 1);
            s8 += __shfl_xor(s8, 2);
            s8 += __shfl_xor(s8, 4);
            float mu = s8 * 0.125f;
            float d = a - mu;
            float vv = d * d;
            vv += __shfl_xor(vv, 1); vv += __shfl_xor(vv, 2); vv += __shfl_xor(vv, 4);
            float inv = rsqrtf(vv * 0.125f + 1e-5f);
            xs[t] = d * inv * l2gs[li * 8 + g] + l2bs[li * 8 + g];
        }
        __syncthreads();
    }

    // ---- head ----
    {
        float* cat = part;               // [0..1017]
        float* partial = part + 4096;    // [16][64]
        const float* rg = rna + (size_t)b * RNAIN;
        for (int i = t; i < RNAIN; i += 1024) cat[i] = rg[i];
        __syncthreads();
        int j = lane;
        int k0 = w * 93;
        int k1 = (k0 + 93 < NCAT) ? (k0 + 93) : NCAT;
        float a = (w == 0) ? bprime[j] : 0.f;
        #pragma unroll 4
        for (int k = k0; k < k1; ++k) {
            float ck = (k < RNAIN) ? cat[k] : xs[k - RNAIN];
            a += ck * WcatT[k * 64 + j];
        }
        partial[w * 64 + j] = a;
        __syncthreads();
        if (t < 64) {
            float s = 0.f;
            #pragma unroll
            for (int ww = 0; ww < 16; ++ww) s += partial[ww * 64 + t];
            h1s[t] = s;
        }
    }
    __syncthreads();
    if (t < 8) {
        float a2 = c2_b[t];
        #pragma unroll 8
        for (int m = 0; m < 64; ++m) a2 += h1s[m] * c2_w[t * 64 + m];
        h2s[t] = a2;
    }
    __syncthreads();
    if (t == 0) {
        float a3 = c3_b[0];
        #pragma unroll
        for (int jj = 0; jj < 8; ++jj) a3 += h2s[jj] * c3_w[jj];
        out[b] = a3;
    }
}

extern "C" void kernel_launch(void* const* d_in, const int* in_sizes, int n_in,
                              void* d_out, int out_size, void* d_ws, size_t ws_size,
                              hipStream_t stream) {
    const float* rna    = (const float*)d_in[0];
    const float* drug   = (const float*)d_in[1];
    const float* lin1_w = (const float*)d_in[2];
    const float* lin1_b = (const float*)d_in[3];
    const float* lin2_w = (const float*)d_in[4];
    const float* lin2_b = (const float*)d_in[5];
    const float* chem_w = (const float*)d_in[6];
    const float* pos_w  = (const float*)d_in[7];
    const float* qkv_w  = (const float*)d_in[8];
    const float* qkv_b  = (const float*)d_in[9];
    const float* out_w  = (const float*)d_in[10];
    const float* out_b  = (const float*)d_in[11];
    const float* ln1_g  = (const float*)d_in[12];
    const float* ln1_b  = (const float*)d_in[13];
    const float* ff1_w  = (const float*)d_in[14];
    const float* ff1_b  = (const float*)d_in[15];
    const float* ff2_w  = (const float*)d_in[16];
    const float* ff2_b  = (const float*)d_in[17];
    const float* ln2_g  = (const float*)d_in[18];
    const float* ln2_b  = (const float*)d_in[19];
    const float* c1_w   = (const float*)d_in[20];
    const float* c1_b   = (const float*)d_in[21];
    const float* c2_w   = (const float*)d_in[22];
    const float* c2_b   = (const float*)d_in[23];
    const float* c3_w   = (const float*)d_in[24];
    const float* c3_b   = (const float*)d_in[25];
    float* ws  = (float*)d_ws;
    float* out = (float*)d_out;

    float* epart          = ws + OFF_EPART;
    const _Float16* w1h   = (const _Float16*)(ws + OFF_W1H);
    const _Float16* a2h   = (const _Float16*)(ws + OFF_A2H);
    const float* WcatT    = ws + OFF_WCATT;
    const float* bprime   = ws + OFF_BPRIME;

    hipLaunchKernelGGL(embed_kernel, dim3(BB * 4), dim3(512), 0, stream,
                       drug, chem_w, epart);
    hipLaunchKernelGGL(prep0_kernel, dim3(257), dim3(256), 0, stream,
                       ff1_w, ff2_w, c1_w, lin2_w, lin1_b, lin2_b, ws);
    hipLaunchKernelGGL(prep1_kernel, dim3(371), dim3(256), 0, stream,
                       lin1_w, c1_w, c1_b, ws);
    hipLaunchKernelGGL(main_kernel, dim3(BB), dim3(1024), 0, stream,
                       epart, pos_w, w1h, a2h, ff1_b,
                       qkv_w, qkv_b, out_w, out_b,
                       ln1_g, ln1_b, ff2_b, ln2_g, ln2_b,
                       rna, WcatT, bprime, c2_w, c2_b, c3_w, c3_b, out);
}